// Round 1
// baseline (1557.984 us; speedup 1.0000x reference)
//
#include <hip/hip_runtime.h>

// Problem constants
#define BB 32
#define TT 512
#define FF 128
#define HID 256
#define TP 1024

// ---------------------------------------------------------------------------
// QKV projection: Q = srcQ^T @ wq^T + bq ; K,V from srcKV.  src layouts are
// [b][c][t] (channel-major, t contiguous).  Outputs [B][T][F] (t-major).
// grid (fg=2, tt=16, b=32), block 256.  64 f x 32 t tile per block.
// ---------------------------------------------------------------------------
__global__ __launch_bounds__(256) void qkv_kernel(
    const float* __restrict__ srcQ, int ldq, long long bsq,
    const float* __restrict__ srcKV, int ldkv, long long bskv,
    const float* __restrict__ wq, const float* __restrict__ bq,
    const float* __restrict__ wk, const float* __restrict__ bk,
    const float* __restrict__ wv, const float* __restrict__ bv,
    float* __restrict__ Qo, float* __restrict__ Ko, float* __restrict__ Vo)
{
    int f0 = blockIdx.x * 64, t0 = blockIdx.y * 32, b = blockIdx.z;
    __shared__ __align__(16) float xq[32][36];   // [t][c] transposed
    __shared__ __align__(16) float xkv[32][36];
    __shared__ __align__(16) float wqs[64][36];  // [f][c]
    __shared__ __align__(16) float wks[64][36];
    __shared__ __align__(16) float wvs[64][36];
    int tid = threadIdx.x;
    int tq = tid >> 5, fq = tid & 31;
    float aq[4][2] = {}, ak[4][2] = {}, av[4][2] = {};

    for (int c0 = 0; c0 < 128; c0 += 32) {
        __syncthreads();
        for (int l = tid; l < 1024; l += 256) {
            int c = l >> 5, t = l & 31;
            xq[t][c]  = srcQ[bsq * b + (size_t)(c0 + c) * ldq + t0 + t];
            xkv[t][c] = srcKV[bskv * b + (size_t)(c0 + c) * ldkv + t0 + t];
        }
        for (int l = tid; l < 2048; l += 256) {
            int r = l >> 5, c = l & 31;
            wqs[r][c] = wq[(f0 + r) * 128 + c0 + c];
            wks[r][c] = wk[(f0 + r) * 128 + c0 + c];
            wvs[r][c] = wv[(f0 + r) * 128 + c0 + c];
        }
        __syncthreads();
        for (int c4 = 0; c4 < 32; c4 += 4) {
            float4 xqv[4], xkvv[4];
#pragma unroll
            for (int i = 0; i < 4; ++i) {
                xqv[i]  = *(const float4*)&xq[tq * 4 + i][c4];
                xkvv[i] = *(const float4*)&xkv[tq * 4 + i][c4];
            }
#pragma unroll
            for (int j = 0; j < 2; ++j) {
                int f = j * 32 + fq;
                float4 wq4 = *(const float4*)&wqs[f][c4];
                float4 wk4 = *(const float4*)&wks[f][c4];
                float4 wv4 = *(const float4*)&wvs[f][c4];
#pragma unroll
                for (int i = 0; i < 4; ++i) {
                    aq[i][j] += xqv[i].x*wq4.x + xqv[i].y*wq4.y + xqv[i].z*wq4.z + xqv[i].w*wq4.w;
                    ak[i][j] += xkvv[i].x*wk4.x + xkvv[i].y*wk4.y + xkvv[i].z*wk4.z + xkvv[i].w*wk4.w;
                    av[i][j] += xkvv[i].x*wv4.x + xkvv[i].y*wv4.y + xkvv[i].z*wv4.z + xkvv[i].w*wv4.w;
                }
            }
        }
    }
#pragma unroll
    for (int j = 0; j < 2; ++j) {
        int f = f0 + j * 32 + fq;
        float bqv = bq[f], bkv = bk[f], bvv = bv[f];
#pragma unroll
        for (int i = 0; i < 4; ++i) {
            int t = t0 + tq * 4 + i;
            size_t o = ((size_t)b * TT + t) * FF + f;
            Qo[o] = aq[i][j] + bqv;
            Ko[o] = ak[i][j] + bkv;
            Vo[o] = av[i][j] + bvv;
        }
    }
}

// ---------------------------------------------------------------------------
// Attention: scores = Q K^T / sqrt(F); softmax; attn = P V;
// result = attn * orig + orig, written in [B][T][F] (out_tf) and into the
// x-buffer half [b][f][1024] at column offset xoff (out_x).
// grid (tt=16, b=32), block 256.  Two-pass softmax with scores tile in LDS.
// ---------------------------------------------------------------------------
__global__ __launch_bounds__(256) void attn_kernel(
    const float* __restrict__ Qb, const float* __restrict__ Kb,
    const float* __restrict__ Vb,
    const float* __restrict__ orig, int ldo, long long bso,
    float* __restrict__ out_tf, float* __restrict__ out_x, int xoff)
{
    int t0 = blockIdx.x * 32, b = blockIdx.y;
    __shared__ __align__(16) float qs[32][132];
    __shared__ __align__(16) float sc[32][513];
    __shared__ __align__(16) float kvb[4224];  // [32][132] K/V tile; later [128][33] orig tile
    int tid = threadIdx.x;

    for (int l = tid; l < 4096; l += 256) {
        int t = l >> 7, f = l & 127;
        qs[t][f] = Qb[((size_t)b * TT + t0 + t) * FF + f];
    }
    const float scale = 0.088388347648318447f;  // 1/sqrt(128)
    int ti2 = tid >> 4, sq2 = tid & 15;

    for (int s0 = 0; s0 < 512; s0 += 32) {
        __syncthreads();
        for (int l = tid; l < 4096; l += 256) {
            int s = l >> 7, f = l & 127;
            kvb[s * 132 + f] = Kb[((size_t)b * TT + s0 + s) * FF + f];
        }
        __syncthreads();
        float acc00 = 0.f, acc01 = 0.f, acc10 = 0.f, acc11 = 0.f;
        for (int f = 0; f < 128; f += 4) {
            float4 q0 = *(const float4*)&qs[ti2 * 2 + 0][f];
            float4 q1 = *(const float4*)&qs[ti2 * 2 + 1][f];
            float4 k0 = *(const float4*)&kvb[sq2 * 132 + f];
            float4 k1 = *(const float4*)&kvb[(16 + sq2) * 132 + f];
            acc00 += q0.x*k0.x + q0.y*k0.y + q0.z*k0.z + q0.w*k0.w;
            acc01 += q0.x*k1.x + q0.y*k1.y + q0.z*k1.z + q0.w*k1.w;
            acc10 += q1.x*k0.x + q1.y*k0.y + q1.z*k0.z + q1.w*k0.w;
            acc11 += q1.x*k1.x + q1.y*k1.y + q1.z*k1.z + q1.w*k1.w;
        }
        sc[ti2 * 2 + 0][s0 + sq2]      = acc00 * scale;
        sc[ti2 * 2 + 0][s0 + 16 + sq2] = acc01 * scale;
        sc[ti2 * 2 + 1][s0 + sq2]      = acc10 * scale;
        sc[ti2 * 2 + 1][s0 + 16 + sq2] = acc11 * scale;
    }
    __syncthreads();

    // softmax: 8-thread teams per row (teams are 8 consecutive lanes, in-wave)
    int ti = tid >> 3, lq = tid & 7;
    {
        float m = -1e30f;
        for (int s = lq; s < 512; s += 8) m = fmaxf(m, sc[ti][s]);
#pragma unroll
        for (int msk = 1; msk < 8; msk <<= 1) m = fmaxf(m, __shfl_xor(m, msk));
        float sum = 0.f;
        for (int s = lq; s < 512; s += 8) {
            float e = __expf(sc[ti][s] - m);
            sc[ti][s] = e;
            sum += e;
        }
#pragma unroll
        for (int msk = 1; msk < 8; msk <<= 1) sum += __shfl_xor(sum, msk);
        float rinv = 1.f / sum;
        for (int s = lq; s < 512; s += 8) sc[ti][s] *= rinv;
    }

    // PV: thread owns row ti, f = jj*32 + lq*4 .. +3 (float4)
    float4 acc4[4];
#pragma unroll
    for (int jj = 0; jj < 4; ++jj) acc4[jj] = make_float4(0.f, 0.f, 0.f, 0.f);
    for (int s0 = 0; s0 < 512; s0 += 32) {
        __syncthreads();
        for (int l = tid; l < 4096; l += 256) {
            int s = l >> 7, f = l & 127;
            kvb[s * 132 + f] = Vb[((size_t)b * TT + s0 + s) * FF + f];
        }
        __syncthreads();
        for (int s = 0; s < 32; ++s) {
            float p = sc[ti][s0 + s];
#pragma unroll
            for (int jj = 0; jj < 4; ++jj) {
                float4 v = *(const float4*)&kvb[s * 132 + jj * 32 + lq * 4];
                acc4[jj].x += p * v.x; acc4[jj].y += p * v.y;
                acc4[jj].z += p * v.z; acc4[jj].w += p * v.w;
            }
        }
    }
    __syncthreads();  // all P reads + V reads done

    // stage attn as att[f][t] into sc's memory; load orig tile into kvb
    float* att = &sc[0][0];
#pragma unroll
    for (int jj = 0; jj < 4; ++jj) {
        int f = jj * 32 + lq * 4;
        att[(f + 0) * 33 + ti] = acc4[jj].x;
        att[(f + 1) * 33 + ti] = acc4[jj].y;
        att[(f + 2) * 33 + ti] = acc4[jj].z;
        att[(f + 3) * 33 + ti] = acc4[jj].w;
    }
    float* xo = kvb;  // [128][33]
    for (int l = tid; l < 4096; l += 256) {
        int c = l >> 5, t = l & 31;
        xo[c * 33 + t] = orig[bso * b + (size_t)c * ldo + t0 + t];
    }
    __syncthreads();

    for (int l = tid; l < 4096; l += 256) {
        int t = l >> 7, f = l & 127;
        float xv = xo[f * 33 + t];
        float r = att[f * 33 + t] * xv + xv;
        out_tf[((size_t)b * TT + t0 + t) * FF + f] = r;
    }
    for (int l = tid; l < 4096; l += 256) {
        int f = l >> 5, t = l & 31;
        float xv = xo[f * 33 + t];
        float r = att[f * 33 + t] * xv + xv;
        out_x[(size_t)b * (FF * TP) + (size_t)f * TP + xoff + t0 + t] = r;
    }
}

// ---------------------------------------------------------------------------
// MMD: block per timepoint t.  loss partial = sum_{i,j} exp(-.5|f1i-f1j|^2)
// + exp(-.5|f2i-f2j|^2) - 2 exp(-.5|f1i-f2j|^2).
// ---------------------------------------------------------------------------
__global__ __launch_bounds__(256) void mmd_kernel(
    const float* __restrict__ f1, const float* __restrict__ f2,
    float* __restrict__ partials)
{
    int t = blockIdx.x;
    __shared__ float v1[32][129], v2[32][129];
    __shared__ float red[256];
    int tid = threadIdx.x;
    for (int l = tid; l < 4096; l += 256) {
        int i = l >> 7, f = l & 127;
        v1[i][f] = f1[((size_t)i * TT + t) * FF + f];
        v2[i][f] = f2[((size_t)i * TT + t) * FF + f];
    }
    __syncthreads();
    float s = 0.f;
    for (int r = 0; r < 4; ++r) {
        int p = tid + 256 * r;
        int i = p >> 5, j = p & 31;
        float dxx = 0.f, dyy = 0.f, dxy = 0.f;
        for (int f = 0; f < 128; ++f) {
            float a = v1[i][f], b_ = v1[j][f], c = v2[i][f], d = v2[j][f];
            float e1 = a - b_, e2 = c - d, e3 = a - d;
            dxx += e1 * e1; dyy += e2 * e2; dxy += e3 * e3;
        }
        s += __expf(-0.5f * dxx) + __expf(-0.5f * dyy) - 2.f * __expf(-0.5f * dxy);
    }
    red[tid] = s;
    __syncthreads();
    for (int off = 128; off; off >>= 1) {
        if (tid < off) red[tid] += red[tid + off];
        __syncthreads();
    }
    if (tid == 0) partials[t] = red[0];
}

// ---------------------------------------------------------------------------
// TCN layer: out[b,o,t] = relu(sum_{c,k} x[b,c,t-(2-k)d] cw[o,c,k] + cb[o])
//                       + sum_c x[b,c,t] rw[o,c] + rb[o]
// implicit GEMM; grid (tt=16, og=4, b=32); block 256; 64o x 64t tile.
// ---------------------------------------------------------------------------
__global__ __launch_bounds__(256) void tcn_kernel(
    const float* __restrict__ x, int Cin, int d,
    const float* __restrict__ cw, const float* __restrict__ cb,
    const float* __restrict__ rw, const float* __restrict__ rb,
    float* __restrict__ out)
{
    int t0 = blockIdx.x * 64, o0 = blockIdx.y * 64, b = blockIdx.z;
    __shared__ float xs[32][73];                 // [c][col], col base = t0-2d
    __shared__ __align__(16) float cwk[3][64][36];  // per-k plane, [o][c]
    __shared__ __align__(16) float rws[64][36];
    int tid = threadIdx.x;
    int to = tid & 15, tq = tid >> 4;
    float accc[4][4] = {}, accr[4][4] = {};
    int d2 = 2 * d;

    for (int c0 = 0; c0 < Cin; c0 += 32) {
        __syncthreads();
        for (int l = tid; l < 32 * 73; l += 256) {
            int c = l / 73, col = l % 73;
            int tg = t0 - d2 + col;
            float v = 0.f;
            if (tg >= 0 && tg < TP) v = x[((size_t)b * Cin + c0 + c) * TP + tg];
            xs[c][col] = v;
        }
        for (int l = tid; l < 2048; l += 256) {
            int r = l >> 5, c = l & 31;
            size_t gi = ((size_t)(o0 + r) * Cin + c0 + c) * 3;
            cwk[0][r][c] = cw[gi + 0];
            cwk[1][r][c] = cw[gi + 1];
            cwk[2][r][c] = cw[gi + 2];
            rws[r][c] = rw[(size_t)(o0 + r) * Cin + c0 + c];
        }
        __syncthreads();
        for (int c4 = 0; c4 < 32; c4 += 4) {
            float xa[4][4], xb[4][4], xc[4][4];  // [cc][i], taps k=0,1,2
#pragma unroll
            for (int cc = 0; cc < 4; ++cc) {
#pragma unroll
                for (int i = 0; i < 4; ++i) {
                    int tl = tq * 4 + i;
                    xa[cc][i] = xs[c4 + cc][tl];
                    xb[cc][i] = xs[c4 + cc][tl + d];
                    xc[cc][i] = xs[c4 + cc][tl + d2];
                }
            }
#pragma unroll
            for (int j = 0; j < 4; ++j) {
                int o = j * 16 + to;
                float4 w0 = *(const float4*)&cwk[0][o][c4];
                float4 w1 = *(const float4*)&cwk[1][o][c4];
                float4 w2 = *(const float4*)&cwk[2][o][c4];
                float4 wr = *(const float4*)&rws[o][c4];
#pragma unroll
                for (int i = 0; i < 4; ++i) {
                    accc[i][j] += w0.x*xa[0][i] + w1.x*xb[0][i] + w2.x*xc[0][i]
                                + w0.y*xa[1][i] + w1.y*xb[1][i] + w2.y*xc[1][i]
                                + w0.z*xa[2][i] + w1.z*xb[2][i] + w2.z*xc[2][i]
                                + w0.w*xa[3][i] + w1.w*xb[3][i] + w2.w*xc[3][i];
                    accr[i][j] += wr.x*xc[0][i] + wr.y*xc[1][i]
                                + wr.z*xc[2][i] + wr.w*xc[3][i];
                }
            }
        }
    }
#pragma unroll
    for (int j = 0; j < 4; ++j) {
        int o = o0 + j * 16 + to;
        float cbv = cb[o], rbv = rb[o];
#pragma unroll
        for (int i = 0; i < 4; ++i) {
            int t = t0 + tq * 4 + i;
            out[((size_t)b * HID + o) * TP + t] = fmaxf(accc[i][j] + cbv, 0.f) + accr[i][j] + rbv;
        }
    }
}

// ---------------------------------------------------------------------------
// pool: mean over t (1024) per (b, o).  grid (256, 32), block 64 (1 wave).
// ---------------------------------------------------------------------------
__global__ __launch_bounds__(64) void pool_kernel(
    const float* __restrict__ h, float* __restrict__ pooled)
{
    int o = blockIdx.x, b = blockIdx.y;
    int lane = threadIdx.x;
    const float* row = h + ((size_t)b * HID + o) * TP;
    float s = 0.f;
    for (int r = 0; r < 16; ++r) s += row[lane + 64 * r];
    for (int off = 32; off; off >>= 1) s += __shfl_down(s, off);
    if (lane == 0) pooled[b * HID + o] = s * (1.f / 1024.f);
}

// ---------------------------------------------------------------------------
// final: out[b,k] = pooled[b] . fc_w[k] + fc_b[k]  (128 outputs)
//        d_out[128] = sum(partials)/ (B*B*T)
// ---------------------------------------------------------------------------
__global__ __launch_bounds__(256) void final_kernel(
    const float* __restrict__ pooled, const float* __restrict__ fcw,
    const float* __restrict__ fcb, const float* __restrict__ partials,
    float* __restrict__ dout)
{
    int tid = threadIdx.x;
    if (tid < 128) {
        int b = tid >> 2, k = tid & 3;
        float s = fcb[k];
        for (int o = 0; o < 256; ++o) s += pooled[b * HID + o] * fcw[k * HID + o];
        dout[tid] = s;
    } else if (tid < 192) {
        int lane = tid - 128;
        float s = 0.f;
        for (int j = 0; j < 8; ++j) s += partials[lane + 64 * j];
        for (int off = 32; off; off >>= 1) s += __shfl_down(s, off);
        if (lane == 0) dout[128] = s * (1.f / (32.f * 32.f * 512.f));
    }
}

// ---------------------------------------------------------------------------
extern "C" void kernel_launch(void* const* d_in, const int* in_sizes, int n_in,
                              void* d_out, int out_size, void* d_ws, size_t ws_size,
                              hipStream_t stream)
{
    const float* feat1 = (const float*)d_in[0];
    const float* feat2 = (const float*)d_in[1];
    const float* wq_a = (const float*)d_in[2];
    const float* bq_a = (const float*)d_in[3];
    const float* wk_a = (const float*)d_in[4];
    const float* bk_a = (const float*)d_in[5];
    const float* wv_a = (const float*)d_in[6];
    const float* bv_a = (const float*)d_in[7];
    const float* wq_b = (const float*)d_in[8];
    const float* bq_b = (const float*)d_in[9];
    const float* wk_b = (const float*)d_in[10];
    const float* bk_b = (const float*)d_in[11];
    const float* wv_b = (const float*)d_in[12];
    const float* bv_b = (const float*)d_in[13];
    const float* cw0 = (const float*)d_in[14];
    const float* cb0 = (const float*)d_in[15];
    const float* rw0 = (const float*)d_in[16];
    const float* rb0 = (const float*)d_in[17];
    const float* cw1 = (const float*)d_in[18];
    const float* cb1 = (const float*)d_in[19];
    const float* rw1 = (const float*)d_in[20];
    const float* rb1 = (const float*)d_in[21];
    const float* cw2 = (const float*)d_in[22];
    const float* cb2 = (const float*)d_in[23];
    const float* rw2 = (const float*)d_in[24];
    const float* rb2 = (const float*)d_in[25];
    const float* fcw = (const float*)d_in[26];
    const float* fcb = (const float*)d_in[27];
    float* dout = (float*)d_out;

    // workspace layout (floats):
    //   slabA [0, 8388608):     Q, K, V (each 2097152) during attention; h0 after
    //   slabB [8388608, 16777216): f1tf, f2tf (2097152 each), xbuf (4194304);
    //                               h1 aliases whole slabB (TCN layer 1 output)
    //   [16777216, +8192): pooled; then 512 floats of MMD partials
    float* ws = (float*)d_ws;
    float* Q    = ws;
    float* K    = ws + 2097152;
    float* V    = ws + 4194304;
    float* h0   = ws;                // 8388608 floats
    float* f1tf = ws + 8388608;
    float* f2tf = ws + 10485760;
    float* xbuf = ws + 12582912;     // [32][128][1024]
    float* h1   = ws + 8388608;      // aliases slabB
    float* pooled   = ws + 16777216;
    float* partials = ws + 16777216 + 8192;

    // branch A: Q from feat2, K/V from feat1; updates f1
    qkv_kernel<<<dim3(2, 16, 32), 256, 0, stream>>>(
        feat2, TT, (long long)FF * TT, feat1, TT, (long long)FF * TT,
        wq_a, bq_a, wk_a, bk_a, wv_a, bv_a, Q, K, V);
    attn_kernel<<<dim3(16, 32), 256, 0, stream>>>(
        Q, K, V, feat1, TT, (long long)FF * TT, f1tf, xbuf, 0);

    // branch B: Q from updated f1 (xbuf half A, ld 1024), K/V from feat2; updates f2
    qkv_kernel<<<dim3(2, 16, 32), 256, 0, stream>>>(
        xbuf, TP, (long long)FF * TP, feat2, TT, (long long)FF * TT,
        wq_b, bq_b, wk_b, bk_b, wv_b, bv_b, Q, K, V);
    attn_kernel<<<dim3(16, 32), 256, 0, stream>>>(
        Q, K, V, feat2, TT, (long long)FF * TT, f2tf, xbuf, 512);

    // MMD partials (must precede TCN layer 1, which overwrites slabB)
    mmd_kernel<<<dim3(512), 256, 0, stream>>>(f1tf, f2tf, partials);

    // TCN stack: x(128ch) -> h0 -> h1 -> h0
    tcn_kernel<<<dim3(16, 4, 32), 256, 0, stream>>>(xbuf, 128, 1, cw0, cb0, rw0, rb0, h0);
    tcn_kernel<<<dim3(16, 4, 32), 256, 0, stream>>>(h0, 256, 2, cw1, cb1, rw1, rb1, h1);
    tcn_kernel<<<dim3(16, 4, 32), 256, 0, stream>>>(h1, 256, 4, cw2, cb2, rw2, rb2, h0);

    pool_kernel<<<dim3(256, 32), 64, 0, stream>>>(h0, pooled);
    final_kernel<<<dim3(1), 256, 0, stream>>>(pooled, fcw, fcb, partials, dout);
}

// Round 2
// 819.698 us; speedup vs baseline: 1.9007x; 1.9007x over previous
//
#include <hip/hip_runtime.h>

#define BB 32
#define TT 512
#define FF 128
#define HID 256
#define TP 1024

typedef __attribute__((ext_vector_type(8))) short s16x8;
typedef __attribute__((ext_vector_type(8))) unsigned short u16x8;
typedef __attribute__((ext_vector_type(4))) unsigned short u16x4;
typedef __attribute__((ext_vector_type(4))) float f32x4;

static __device__ __forceinline__ unsigned short f2bf(float f) {
    unsigned u = __builtin_bit_cast(unsigned, f);
    u = (u + 0x7FFFu + ((u >> 16) & 1u)) >> 16;
    return (unsigned short)u;
}
static __device__ __forceinline__ float bf2f(unsigned short b) {
    return __builtin_bit_cast(float, ((unsigned)b) << 16);
}

// ---------------------------------------------------------------------------
// QKV projection.  src element (b,c,t) at b*bs + c*cs + t*ts (fp32).
// Outputs [B][T][F].  grid (2, 16, 32), block 256.
// ---------------------------------------------------------------------------
__global__ __launch_bounds__(256) void qkv_kernel(
    const float* __restrict__ srcQ, long long bsq, int csq, int tsq,
    const float* __restrict__ srcKV, long long bskv, int cskv, int tskv,
    const float* __restrict__ wq, const float* __restrict__ bq,
    const float* __restrict__ wk, const float* __restrict__ bk,
    const float* __restrict__ wv, const float* __restrict__ bv,
    float* __restrict__ Qo, float* __restrict__ Ko, float* __restrict__ Vo)
{
    int f0 = blockIdx.x * 64, t0 = blockIdx.y * 32, b = blockIdx.z;
    __shared__ __align__(16) float xq[32][36];   // [t][c]
    __shared__ __align__(16) float xkv[32][36];
    __shared__ __align__(16) float wqs[64][36];  // [f][c]
    __shared__ __align__(16) float wks[64][36];
    __shared__ __align__(16) float wvs[64][36];
    int tid = threadIdx.x;
    int tq = tid >> 5, fq = tid & 31;
    float aq[4][2] = {}, ak[4][2] = {}, av[4][2] = {};

    for (int c0 = 0; c0 < 128; c0 += 32) {
        __syncthreads();
        for (int l = tid; l < 1024; l += 256) {
            int c = l >> 5, t = l & 31;
            xq[t][c]  = srcQ[bsq * b + (size_t)(c0 + c) * csq + (size_t)(t0 + t) * tsq];
            xkv[t][c] = srcKV[bskv * b + (size_t)(c0 + c) * cskv + (size_t)(t0 + t) * tskv];
        }
        for (int l = tid; l < 2048; l += 256) {
            int r = l >> 5, c = l & 31;
            wqs[r][c] = wq[(f0 + r) * 128 + c0 + c];
            wks[r][c] = wk[(f0 + r) * 128 + c0 + c];
            wvs[r][c] = wv[(f0 + r) * 128 + c0 + c];
        }
        __syncthreads();
        for (int c4 = 0; c4 < 32; c4 += 4) {
            float4 xqv[4], xkvv[4];
#pragma unroll
            for (int i = 0; i < 4; ++i) {
                xqv[i]  = *(const float4*)&xq[tq * 4 + i][c4];
                xkvv[i] = *(const float4*)&xkv[tq * 4 + i][c4];
            }
#pragma unroll
            for (int j = 0; j < 2; ++j) {
                int f = j * 32 + fq;
                float4 wq4 = *(const float4*)&wqs[f][c4];
                float4 wk4 = *(const float4*)&wks[f][c4];
                float4 wv4 = *(const float4*)&wvs[f][c4];
#pragma unroll
                for (int i = 0; i < 4; ++i) {
                    aq[i][j] += xqv[i].x*wq4.x + xqv[i].y*wq4.y + xqv[i].z*wq4.z + xqv[i].w*wq4.w;
                    ak[i][j] += xkvv[i].x*wk4.x + xkvv[i].y*wk4.y + xkvv[i].z*wk4.z + xkvv[i].w*wk4.w;
                    av[i][j] += xkvv[i].x*wv4.x + xkvv[i].y*wv4.y + xkvv[i].z*wv4.z + xkvv[i].w*wv4.w;
                }
            }
        }
    }
#pragma unroll
    for (int j = 0; j < 2; ++j) {
        int f = f0 + j * 32 + fq;
        float bqv = bq[f], bkv = bk[f], bvv = bv[f];
#pragma unroll
        for (int i = 0; i < 4; ++i) {
            int t = t0 + tq * 4 + i;
            size_t o = ((size_t)b * TT + t) * FF + f;
            Qo[o] = aq[i][j] + bqv;
            Ko[o] = ak[i][j] + bkv;
            Vo[o] = av[i][j] + bvv;
        }
    }
}

// ---------------------------------------------------------------------------
// Attention: scores = Q K^T / sqrt(F); softmax; attn = P V;
// result = attn*orig + orig -> out_tf fp32 [B][T][F] and out_x bf16 [b][t][c]
// at row offset xoff.  grid (16, 32), block 256.
// ---------------------------------------------------------------------------
__global__ __launch_bounds__(256) void attn_kernel(
    const float* __restrict__ Qb, const float* __restrict__ Kb,
    const float* __restrict__ Vb,
    const float* __restrict__ orig, int ldo, long long bso,
    float* __restrict__ out_tf, unsigned short* __restrict__ out_x, int xoff)
{
    int t0 = blockIdx.x * 32, b = blockIdx.y;
    __shared__ __align__(16) float qs[32][132];
    __shared__ __align__(16) float sc[32][513];
    __shared__ __align__(16) float kvb[4224];
    int tid = threadIdx.x;

    for (int l = tid; l < 4096; l += 256) {
        int t = l >> 7, f = l & 127;
        qs[t][f] = Qb[((size_t)b * TT + t0 + t) * FF + f];
    }
    const float scale = 0.088388347648318447f;
    int ti2 = tid >> 4, sq2 = tid & 15;

    for (int s0 = 0; s0 < 512; s0 += 32) {
        __syncthreads();
        for (int l = tid; l < 4096; l += 256) {
            int s = l >> 7, f = l & 127;
            kvb[s * 132 + f] = Kb[((size_t)b * TT + s0 + s) * FF + f];
        }
        __syncthreads();
        float acc00 = 0.f, acc01 = 0.f, acc10 = 0.f, acc11 = 0.f;
        for (int f = 0; f < 128; f += 4) {
            float4 q0 = *(const float4*)&qs[ti2 * 2 + 0][f];
            float4 q1 = *(const float4*)&qs[ti2 * 2 + 1][f];
            float4 k0 = *(const float4*)&kvb[sq2 * 132 + f];
            float4 k1 = *(const float4*)&kvb[(16 + sq2) * 132 + f];
            acc00 += q0.x*k0.x + q0.y*k0.y + q0.z*k0.z + q0.w*k0.w;
            acc01 += q0.x*k1.x + q0.y*k1.y + q0.z*k1.z + q0.w*k1.w;
            acc10 += q1.x*k0.x + q1.y*k0.y + q1.z*k0.z + q1.w*k0.w;
            acc11 += q1.x*k1.x + q1.y*k1.y + q1.z*k1.z + q1.w*k1.w;
        }
        sc[ti2 * 2 + 0][s0 + sq2]      = acc00 * scale;
        sc[ti2 * 2 + 0][s0 + 16 + sq2] = acc01 * scale;
        sc[ti2 * 2 + 1][s0 + sq2]      = acc10 * scale;
        sc[ti2 * 2 + 1][s0 + 16 + sq2] = acc11 * scale;
    }
    __syncthreads();

    int ti = tid >> 3, lq = tid & 7;
    {
        float m = -1e30f;
        for (int s = lq; s < 512; s += 8) m = fmaxf(m, sc[ti][s]);
#pragma unroll
        for (int msk = 1; msk < 8; msk <<= 1) m = fmaxf(m, __shfl_xor(m, msk));
        float sum = 0.f;
        for (int s = lq; s < 512; s += 8) {
            float e = __expf(sc[ti][s] - m);
            sc[ti][s] = e;
            sum += e;
        }
#pragma unroll
        for (int msk = 1; msk < 8; msk <<= 1) sum += __shfl_xor(sum, msk);
        float rinv = 1.f / sum;
        for (int s = lq; s < 512; s += 8) sc[ti][s] *= rinv;
    }

    float4 acc4[4];
#pragma unroll
    for (int jj = 0; jj < 4; ++jj) acc4[jj] = make_float4(0.f, 0.f, 0.f, 0.f);
    for (int s0 = 0; s0 < 512; s0 += 32) {
        __syncthreads();
        for (int l = tid; l < 4096; l += 256) {
            int s = l >> 7, f = l & 127;
            kvb[s * 132 + f] = Vb[((size_t)b * TT + s0 + s) * FF + f];
        }
        __syncthreads();
        for (int s = 0; s < 32; ++s) {
            float p = sc[ti][s0 + s];
#pragma unroll
            for (int jj = 0; jj < 4; ++jj) {
                float4 v = *(const float4*)&kvb[s * 132 + jj * 32 + lq * 4];
                acc4[jj].x += p * v.x; acc4[jj].y += p * v.y;
                acc4[jj].z += p * v.z; acc4[jj].w += p * v.w;
            }
        }
    }
    __syncthreads();

    float* att = &sc[0][0];
#pragma unroll
    for (int jj = 0; jj < 4; ++jj) {
        int f = jj * 32 + lq * 4;
        att[(f + 0) * 33 + ti] = acc4[jj].x;
        att[(f + 1) * 33 + ti] = acc4[jj].y;
        att[(f + 2) * 33 + ti] = acc4[jj].z;
        att[(f + 3) * 33 + ti] = acc4[jj].w;
    }
    float* xo = kvb;  // [128][33]
    for (int l = tid; l < 4096; l += 256) {
        int c = l >> 5, t = l & 31;
        xo[c * 33 + t] = orig[bso * b + (size_t)c * ldo + t0 + t];
    }
    __syncthreads();

    for (int l = tid; l < 4096; l += 256) {
        int t = l >> 7, f = l & 127;
        float xv = xo[f * 33 + t];
        float r = att[f * 33 + t] * xv + xv;
        out_tf[((size_t)b * TT + t0 + t) * FF + f] = r;
        out_x[((size_t)b * TP + xoff + t0 + t) * FF + f] = f2bf(r);
    }
}

// ---------------------------------------------------------------------------
// MMD partials per timepoint.
// ---------------------------------------------------------------------------
__global__ __launch_bounds__(256) void mmd_kernel(
    const float* __restrict__ f1, const float* __restrict__ f2,
    float* __restrict__ partials)
{
    int t = blockIdx.x;
    __shared__ float v1[32][129], v2[32][129];
    __shared__ float red[256];
    int tid = threadIdx.x;
    for (int l = tid; l < 4096; l += 256) {
        int i = l >> 7, f = l & 127;
        v1[i][f] = f1[((size_t)i * TT + t) * FF + f];
        v2[i][f] = f2[((size_t)i * TT + t) * FF + f];
    }
    __syncthreads();
    float s = 0.f;
    for (int r = 0; r < 4; ++r) {
        int p = tid + 256 * r;
        int i = p >> 5, j = p & 31;
        float dxx = 0.f, dyy = 0.f, dxy = 0.f;
        for (int f = 0; f < 128; ++f) {
            float a = v1[i][f], b_ = v1[j][f], c = v2[i][f], d = v2[j][f];
            float e1 = a - b_, e2 = c - d, e3 = a - d;
            dxx += e1 * e1; dyy += e2 * e2; dxy += e3 * e3;
        }
        s += __expf(-0.5f * dxx) + __expf(-0.5f * dyy) - 2.f * __expf(-0.5f * dxy);
    }
    red[tid] = s;
    __syncthreads();
    for (int off = 128; off; off >>= 1) {
        if (tid < off) red[tid] += red[tid + off];
        __syncthreads();
    }
    if (tid == 0) partials[t] = red[0];
}

// ---------------------------------------------------------------------------
// weight prep: w4[plane][o][c] bf16, planes 0..2 = conv taps, 3 = residual.
// ---------------------------------------------------------------------------
__global__ __launch_bounds__(256) void prep_w_kernel(
    const float* __restrict__ cw, const float* __restrict__ rw,
    unsigned short* __restrict__ out, int Cin)
{
    int idx = blockIdx.x * 256 + threadIdx.x;
    int total = 4 * 256 * Cin;
    if (idx >= total) return;
    int p = idx / (256 * Cin);
    int rem = idx - p * 256 * Cin;
    int o = rem / Cin, c = rem - o * Cin;
    float v = (p < 3) ? cw[(o * Cin + c) * 3 + p] : rw[o * Cin + c];
    out[idx] = f2bf(v);
}

// ---------------------------------------------------------------------------
// TCN layer via MFMA.  x bf16 [b][t][Cin]; w4 bf16 [4][256][Cin];
// out bf16 [b][t][256].  out = relu(conv + cb) + res + rb.
// grid (4 t-tiles, 4 o-tiles, 32 b), block 256 (4 waves).
// wave tile: 64 o x 64 t.  LDS holds x-tile [264 rows][32 c] pitch 40 ushorts.
// ---------------------------------------------------------------------------
__global__ __launch_bounds__(256) void tcn_mfma_kernel(
    const unsigned short* __restrict__ x, int Cin, int d,
    const unsigned short* __restrict__ w4,
    const float* __restrict__ cb, const float* __restrict__ rb,
    unsigned short* __restrict__ out)
{
    int t0 = blockIdx.x * 256, o0 = blockIdx.y * 64, b = blockIdx.z;
    __shared__ __align__(16) unsigned short xs[264 * 40];
    int tid = threadIdx.x;
    int wid = tid >> 6, lane = tid & 63;
    int n = lane & 15, g = lane >> 4;
    int wt0 = wid * 64;
    int d2 = 2 * d;
    int nrow = 256 + d2;
    const unsigned short* xb = x + (size_t)b * TP * Cin;

    f32x4 accc[4][4], accr[4][4];
#pragma unroll
    for (int i = 0; i < 4; ++i)
#pragma unroll
        for (int j = 0; j < 4; ++j) {
            accc[i][j] = (f32x4){0.f, 0.f, 0.f, 0.f};
            accr[i][j] = (f32x4){0.f, 0.f, 0.f, 0.f};
        }

    for (int c0 = 0; c0 < Cin; c0 += 32) {
        __syncthreads();
        for (int l = tid; l < nrow * 4; l += 256) {
            int row = l >> 2, gg = l & 3;
            int tg = t0 - d2 + row;
            u16x8 v = {0, 0, 0, 0, 0, 0, 0, 0};
            if (tg >= 0 && tg < TP)
                v = *(const u16x8*)&xb[(size_t)tg * Cin + c0 + gg * 8];
            *(u16x8*)&xs[row * 40 + gg * 8] = v;
        }
        __syncthreads();
        s16x8 bf[3][4];
#pragma unroll
        for (int j = 0; j < 4; ++j)
#pragma unroll
            for (int k = 0; k < 3; ++k)
                bf[k][j] = *(const s16x8*)&xs[(wt0 + j * 16 + n + k * d) * 40 + g * 8];
#pragma unroll
        for (int i = 0; i < 4; ++i) {
            const unsigned short* wb = &w4[(size_t)(o0 + i * 16 + n) * Cin + c0 + g * 8];
            size_t ps = (size_t)256 * Cin;
            s16x8 a0 = *(const s16x8*)&wb[0];
            s16x8 a1 = *(const s16x8*)&wb[ps];
            s16x8 a2 = *(const s16x8*)&wb[2 * ps];
            s16x8 ar = *(const s16x8*)&wb[3 * ps];
#pragma unroll
            for (int j = 0; j < 4; ++j) {
                accc[i][j] = __builtin_amdgcn_mfma_f32_16x16x32_bf16(a0, bf[0][j], accc[i][j], 0, 0, 0);
                accc[i][j] = __builtin_amdgcn_mfma_f32_16x16x32_bf16(a1, bf[1][j], accc[i][j], 0, 0, 0);
                accc[i][j] = __builtin_amdgcn_mfma_f32_16x16x32_bf16(a2, bf[2][j], accc[i][j], 0, 0, 0);
                accr[i][j] = __builtin_amdgcn_mfma_f32_16x16x32_bf16(ar, bf[2][j], accr[i][j], 0, 0, 0);
            }
        }
    }
    // epilogue: D row (o-local) = g*4 + reg, col (t-local) = n
#pragma unroll
    for (int i = 0; i < 4; ++i) {
        int ob = o0 + i * 16 + g * 4;
        float c0b = cb[ob], c1b = cb[ob + 1], c2b = cb[ob + 2], c3b = cb[ob + 3];
        float r0b = rb[ob], r1b = rb[ob + 1], r2b = rb[ob + 2], r3b = rb[ob + 3];
#pragma unroll
        for (int j = 0; j < 4; ++j) {
            int t = t0 + wt0 + j * 16 + n;
            u16x4 pk;
            pk[0] = f2bf(fmaxf(accc[i][j][0] + c0b, 0.f) + accr[i][j][0] + r0b);
            pk[1] = f2bf(fmaxf(accc[i][j][1] + c1b, 0.f) + accr[i][j][1] + r1b);
            pk[2] = f2bf(fmaxf(accc[i][j][2] + c2b, 0.f) + accr[i][j][2] + r2b);
            pk[3] = f2bf(fmaxf(accc[i][j][3] + c3b, 0.f) + accr[i][j][3] + r3b);
            *(u16x4*)&out[((size_t)b * TP + t) * HID + ob] = pk;
        }
    }
}

// ---------------------------------------------------------------------------
// pool partials: block (tslice, b); thread = channel; sum 256 t.
// ---------------------------------------------------------------------------
__global__ __launch_bounds__(256) void pool_kernel(
    const unsigned short* __restrict__ h, float* __restrict__ pp)
{
    int ts = blockIdx.x, b = blockIdx.y;
    int c = threadIdx.x;
    const unsigned short* base = h + ((size_t)b * TP + ts * 256) * HID + c;
    float s = 0.f;
    for (int t = 0; t < 256; ++t) s += bf2f(base[(size_t)t * HID]);
    pp[(b * 4 + ts) * HID + c] = s;
}

// ---------------------------------------------------------------------------
// final: fc on pooled means + MMD reduce.
// ---------------------------------------------------------------------------
__global__ __launch_bounds__(256) void final_kernel(
    const float* __restrict__ pp, const float* __restrict__ fcw,
    const float* __restrict__ fcb, const float* __restrict__ partials,
    float* __restrict__ dout)
{
    int tid = threadIdx.x;
    if (tid < 128) {
        int b = tid >> 2, k = tid & 3;
        float s = 0.f;
        for (int c = 0; c < HID; ++c) {
            float pc = pp[(b * 4 + 0) * HID + c] + pp[(b * 4 + 1) * HID + c]
                     + pp[(b * 4 + 2) * HID + c] + pp[(b * 4 + 3) * HID + c];
            s += pc * fcw[k * HID + c];
        }
        dout[tid] = fcb[k] + s * (1.f / 1024.f);
    } else if (tid < 192) {
        int lane = tid - 128;
        float s = 0.f;
        for (int j = 0; j < 8; ++j) s += partials[lane + 64 * j];
        for (int off = 32; off; off >>= 1) s += __shfl_down(s, off);
        if (lane == 0) dout[128] = s * (1.f / (32.f * 32.f * 512.f));
    }
}

// ---------------------------------------------------------------------------
extern "C" void kernel_launch(void* const* d_in, const int* in_sizes, int n_in,
                              void* d_out, int out_size, void* d_ws, size_t ws_size,
                              hipStream_t stream)
{
    const float* feat1 = (const float*)d_in[0];
    const float* feat2 = (const float*)d_in[1];
    const float* wq_a = (const float*)d_in[2];
    const float* bq_a = (const float*)d_in[3];
    const float* wk_a = (const float*)d_in[4];
    const float* bk_a = (const float*)d_in[5];
    const float* wv_a = (const float*)d_in[6];
    const float* bv_a = (const float*)d_in[7];
    const float* wq_b = (const float*)d_in[8];
    const float* bq_b = (const float*)d_in[9];
    const float* wk_b = (const float*)d_in[10];
    const float* bk_b = (const float*)d_in[11];
    const float* wv_b = (const float*)d_in[12];
    const float* bv_b = (const float*)d_in[13];
    const float* cw0 = (const float*)d_in[14];
    const float* cb0 = (const float*)d_in[15];
    const float* rw0 = (const float*)d_in[16];
    const float* rb0 = (const float*)d_in[17];
    const float* cw1 = (const float*)d_in[18];
    const float* cb1 = (const float*)d_in[19];
    const float* rw1 = (const float*)d_in[20];
    const float* rb1 = (const float*)d_in[21];
    const float* cw2 = (const float*)d_in[22];
    const float* cb2 = (const float*)d_in[23];
    const float* rw2 = (const float*)d_in[24];
    const float* rb2 = (const float*)d_in[25];
    const float* fcw = (const float*)d_in[26];
    const float* fcb = (const float*)d_in[27];
    float* dout = (float*)d_out;

    // workspace layout (float offsets):
    //   Q = 0, K = 2097152, V = 4194304          (fp32, dead after attnB)
    //   f1tf = 6291456, f2tf = 8388608           (fp32, dead after mmd)
    //   xbuf = 10485760  (bf16 [32][1024][128] = 4194304 ushorts)
    //   wbuf = 12582912  (bf16, 655360 ushorts: L0 @0, L1 @131072, L2 @393216)
    //   poolpart = 12910592 (32*4*256 fp32), mmdpart = 12943360 (512 fp32)
    //   h_a (bf16 [32][1024][256]) aliases Q+K; h_b aliases f1tf+f2tf.
    float* ws = (float*)d_ws;
    float* Q    = ws;
    float* K    = ws + 2097152;
    float* V    = ws + 4194304;
    float* f1tf = ws + 6291456;
    float* f2tf = ws + 8388608;
    unsigned short* xbuf = (unsigned short*)(ws + 10485760);
    unsigned short* wbuf = (unsigned short*)(ws + 12582912);
    unsigned short* wb0 = wbuf;
    unsigned short* wb1 = wbuf + 131072;
    unsigned short* wb2 = wbuf + 393216;
    float* poolpart = ws + 12910592;
    float* mmdpart  = ws + 12943360;
    unsigned short* h_a = (unsigned short*)ws;              // 4194304 floats
    unsigned short* h_b = (unsigned short*)(ws + 6291456);  // 4194304 floats

    // branch A: Q from feat2, K/V from feat1 ([B][F][1][T]: cs=512, ts=1)
    qkv_kernel<<<dim3(2, 16, 32), 256, 0, stream>>>(
        feat2, 65536LL, 512, 1, feat1, 65536LL, 512, 1,
        wq_a, bq_a, wk_a, bk_a, wv_a, bv_a, Q, K, V);
    attn_kernel<<<dim3(16, 32), 256, 0, stream>>>(
        Q, K, V, feat1, TT, 65536LL, f1tf, xbuf, 0);

    // branch B: Q from updated f1 (f1tf [B][T][F]: cs=1, ts=128), K/V from feat2
    qkv_kernel<<<dim3(2, 16, 32), 256, 0, stream>>>(
        f1tf, 65536LL, 1, 128, feat2, 65536LL, 512, 1,
        wq_b, bq_b, wk_b, bk_b, wv_b, bv_b, Q, K, V);
    attn_kernel<<<dim3(16, 32), 256, 0, stream>>>(
        Q, K, V, feat2, TT, 65536LL, f2tf, xbuf, 512);

    // MMD partials (before TCN layer 1 overwrites f1tf/f2tf)
    mmd_kernel<<<dim3(512), 256, 0, stream>>>(f1tf, f2tf, mmdpart);

    // weight prep (bf16 planes)
    prep_w_kernel<<<dim3(512), 256, 0, stream>>>(cw0, rw0, wb0, 128);
    prep_w_kernel<<<dim3(1024), 256, 0, stream>>>(cw1, rw1, wb1, 256);
    prep_w_kernel<<<dim3(1024), 256, 0, stream>>>(cw2, rw2, wb2, 256);

    // TCN stack: xbuf(128ch) -> h_a -> h_b -> h_a
    tcn_mfma_kernel<<<dim3(4, 4, 32), 256, 0, stream>>>(xbuf, 128, 1, wb0, cb0, rb0, h_a);
    tcn_mfma_kernel<<<dim3(4, 4, 32), 256, 0, stream>>>(h_a, 256, 2, wb1, cb1, rb1, h_b);
    tcn_mfma_kernel<<<dim3(4, 4, 32), 256, 0, stream>>>(h_b, 256, 4, wb2, cb2, rb2, h_a);

    pool_kernel<<<dim3(4, 32), 256, 0, stream>>>(h_a, poolpart);
    final_kernel<<<dim3(1), 256, 0, stream>>>(poolpart, fcw, fcb, mmdpart, dout);
}

// Round 3
// 430.067 us; speedup vs baseline: 3.6227x; 1.9060x over previous
//
#include <hip/hip_runtime.h>

#define BB 32
#define TT 512
#define FF 128
#define HID 256
#define TP 1024

typedef __attribute__((ext_vector_type(8))) short s16x8;
typedef __attribute__((ext_vector_type(8))) unsigned short u16x8;
typedef __attribute__((ext_vector_type(4))) unsigned short u16x4;
typedef __attribute__((ext_vector_type(4))) float f32x4;

static __device__ __forceinline__ unsigned short f2bf(float f) {
    unsigned u = __builtin_bit_cast(unsigned, f);
    u = (u + 0x7FFFu + ((u >> 16) & 1u)) >> 16;
    return (unsigned short)u;
}
static __device__ __forceinline__ float bf2f(unsigned short b) {
    return __builtin_bit_cast(float, ((unsigned)b) << 16);
}

// ---------------------------------------------------------------------------
// QKV projection (fp32 math).  src element (b,c,t) at b*bs + c*cs + t*ts.
// Outputs: Qo bf16 [B][T][F] pre-scaled by 1/sqrt(F); Ko bf16 [B][T][F];
// Vt bf16 [B][F][T].  grid (2, 16, 32), block 256.
// ---------------------------------------------------------------------------
__global__ __launch_bounds__(256) void qkv_kernel(
    const float* __restrict__ srcQ, long long bsq, int csq, int tsq,
    const float* __restrict__ srcKV, long long bskv, int cskv, int tskv,
    const float* __restrict__ wq, const float* __restrict__ bq,
    const float* __restrict__ wk, const float* __restrict__ bk,
    const float* __restrict__ wv, const float* __restrict__ bv,
    unsigned short* __restrict__ Qo, unsigned short* __restrict__ Ko,
    unsigned short* __restrict__ Vt)
{
    int f0 = blockIdx.x * 64, t0 = blockIdx.y * 32, b = blockIdx.z;
    __shared__ __align__(16) float xq[32][36];   // [t][c]
    __shared__ __align__(16) float xkv[32][36];
    __shared__ __align__(16) float wqs[64][36];  // [f][c]
    __shared__ __align__(16) float wks[64][36];
    __shared__ __align__(16) float wvs[64][36];
    int tid = threadIdx.x;
    int tq = tid >> 5, fq = tid & 31;
    float aq[4][2] = {}, ak[4][2] = {}, av[4][2] = {};

    for (int c0 = 0; c0 < 128; c0 += 32) {
        __syncthreads();
        for (int l = tid; l < 1024; l += 256) {
            int c = l >> 5, t = l & 31;
            xq[t][c]  = srcQ[bsq * b + (size_t)(c0 + c) * csq + (size_t)(t0 + t) * tsq];
            xkv[t][c] = srcKV[bskv * b + (size_t)(c0 + c) * cskv + (size_t)(t0 + t) * tskv];
        }
        for (int l = tid; l < 2048; l += 256) {
            int r = l >> 5, c = l & 31;
            wqs[r][c] = wq[(f0 + r) * 128 + c0 + c];
            wks[r][c] = wk[(f0 + r) * 128 + c0 + c];
            wvs[r][c] = wv[(f0 + r) * 128 + c0 + c];
        }
        __syncthreads();
        for (int c4 = 0; c4 < 32; c4 += 4) {
            float4 xqv[4], xkvv[4];
#pragma unroll
            for (int i = 0; i < 4; ++i) {
                xqv[i]  = *(const float4*)&xq[tq * 4 + i][c4];
                xkvv[i] = *(const float4*)&xkv[tq * 4 + i][c4];
            }
#pragma unroll
            for (int j = 0; j < 2; ++j) {
                int f = j * 32 + fq;
                float4 wq4 = *(const float4*)&wqs[f][c4];
                float4 wk4 = *(const float4*)&wks[f][c4];
                float4 wv4 = *(const float4*)&wvs[f][c4];
#pragma unroll
                for (int i = 0; i < 4; ++i) {
                    aq[i][j] += xqv[i].x*wq4.x + xqv[i].y*wq4.y + xqv[i].z*wq4.z + xqv[i].w*wq4.w;
                    ak[i][j] += xkvv[i].x*wk4.x + xkvv[i].y*wk4.y + xkvv[i].z*wk4.z + xkvv[i].w*wk4.w;
                    av[i][j] += xkvv[i].x*wv4.x + xkvv[i].y*wv4.y + xkvv[i].z*wv4.z + xkvv[i].w*wv4.w;
                }
            }
        }
    }
    const float scale = 0.088388347648318447f;  // 1/sqrt(128)
#pragma unroll
    for (int j = 0; j < 2; ++j) {
        int f = f0 + j * 32 + fq;
        float bqv = bq[f], bkv = bk[f], bvv = bv[f];
        u16x4 pv;
#pragma unroll
        for (int i = 0; i < 4; ++i) {
            int t = t0 + tq * 4 + i;
            size_t o = ((size_t)b * TT + t) * FF + f;
            Qo[o] = f2bf((aq[i][j] + bqv) * scale);
            Ko[o] = f2bf(ak[i][j] + bkv);
            pv[i] = f2bf(av[i][j] + bvv);
        }
        *(u16x4*)&Vt[((size_t)b * FF + f) * TT + t0 + tq * 4] = pv;
    }
}

// ---------------------------------------------------------------------------
// Flash attention via MFMA.  Q bf16 [B][T][F] (pre-scaled), K bf16 [B][T][F],
// Vt bf16 [B][F][T].  out = attn*orig + orig -> out_tf fp32 [B][T][F] and
// out_x bf16 [b][t][c] at row offset xoff.
// grid (8 q-tiles, 32 b), block 256 = 4 waves; wave owns 16 q-rows.
// ---------------------------------------------------------------------------
__global__ __launch_bounds__(256) void attn_mfma_kernel(
    const unsigned short* __restrict__ Qb, const unsigned short* __restrict__ Kb,
    const unsigned short* __restrict__ Vtb,
    const float* __restrict__ orig, long long bso, int cso, int tso,
    float* __restrict__ out_tf, unsigned short* __restrict__ out_x, int xoff)
{
    __shared__ __align__(16) unsigned short Ks[64 * 136];   // [s][f] pitch 136
    __shared__ __align__(16) unsigned short Vs[128 * 72];   // [f][s] pitch 72
    __shared__ __align__(16) unsigned short Ps[4 * 16 * 68];// per-wave [q][s] pitch 68

    int t0 = blockIdx.x * 64, b = blockIdx.y;
    int tid = threadIdx.x;
    int wid = tid >> 6, lane = tid & 63;
    int n = lane & 15, g = lane >> 4;
    int q0 = t0 + wid * 16;
    unsigned short* Pw = &Ps[wid * 1088];

    // Q fragments (held in registers for the whole kernel)
    s16x8 qf[4];
#pragma unroll
    for (int kk = 0; kk < 4; ++kk)
        qf[kk] = *(const s16x8*)&Qb[((size_t)b * TT + q0 + n) * FF + kk * 32 + g * 8];

    // staging registers for K/V tile
    u16x8 kst[4], vst[4];
#pragma unroll
    for (int ii = 0; ii < 4; ++ii) {
        int l = tid + 256 * ii;
        kst[ii] = *(const u16x8*)&Kb[((size_t)b * TT + (l >> 4)) * FF + (l & 15) * 8];
        vst[ii] = *(const u16x8*)&Vtb[((size_t)b * FF + (l >> 3)) * TT + (l & 7) * 8];
    }

    f32x4 O[8];
#pragma unroll
    for (int ft = 0; ft < 8; ++ft) O[ft] = (f32x4){0.f, 0.f, 0.f, 0.f};
    float m[4] = {-1e30f, -1e30f, -1e30f, -1e30f};
    float lsum[4] = {0.f, 0.f, 0.f, 0.f};

    for (int it = 0; it < 8; ++it) {
        __syncthreads();  // previous tile fully consumed
#pragma unroll
        for (int ii = 0; ii < 4; ++ii) {
            int l = tid + 256 * ii;
            *(u16x8*)&Ks[(l >> 4) * 136 + (l & 15) * 8] = kst[ii];
            *(u16x8*)&Vs[(l >> 3) * 72 + (l & 7) * 8] = vst[ii];
        }
        __syncthreads();
        if (it < 7) {
            int s0n = (it + 1) * 64;
#pragma unroll
            for (int ii = 0; ii < 4; ++ii) {
                int l = tid + 256 * ii;
                kst[ii] = *(const u16x8*)&Kb[((size_t)b * TT + s0n + (l >> 4)) * FF + (l & 15) * 8];
                vst[ii] = *(const u16x8*)&Vtb[((size_t)b * FF + (l >> 3)) * TT + s0n + (l & 7) * 8];
            }
        }

        // QK^T: acc[st][reg] = S[q = q0+g*4+reg][s = it*64 + st*16 + n]
        f32x4 acc[4];
#pragma unroll
        for (int st = 0; st < 4; ++st) acc[st] = (f32x4){0.f, 0.f, 0.f, 0.f};
#pragma unroll
        for (int kk = 0; kk < 4; ++kk) {
#pragma unroll
            for (int st = 0; st < 4; ++st) {
                s16x8 kf = *(const s16x8*)&Ks[(st * 16 + n) * 136 + kk * 32 + g * 8];
                acc[st] = __builtin_amdgcn_mfma_f32_16x16x32_bf16(qf[kk], kf, acc[st], 0, 0, 0);
            }
        }

        // online softmax
        float mnew[4], c[4], rs[4];
#pragma unroll
        for (int r = 0; r < 4; ++r) {
            float tm = fmaxf(fmaxf(acc[0][r], acc[1][r]), fmaxf(acc[2][r], acc[3][r]));
#pragma unroll
            for (int msk = 1; msk < 16; msk <<= 1) tm = fmaxf(tm, __shfl_xor(tm, msk));
            mnew[r] = fmaxf(m[r], tm);
            c[r] = __expf(m[r] - mnew[r]);
            m[r] = mnew[r];
            rs[r] = 0.f;
        }
#pragma unroll
        for (int st = 0; st < 4; ++st) {
#pragma unroll
            for (int r = 0; r < 4; ++r) {
                float p = __expf(acc[st][r] - mnew[r]);
                rs[r] += p;
                Pw[(g * 4 + r) * 68 + st * 16 + n] = f2bf(p);
            }
        }
#pragma unroll
        for (int r = 0; r < 4; ++r) {
#pragma unroll
            for (int msk = 1; msk < 16; msk <<= 1) rs[r] += __shfl_xor(rs[r], msk);
            lsum[r] = lsum[r] * c[r] + rs[r];
        }
#pragma unroll
        for (int ft = 0; ft < 8; ++ft) {
#pragma unroll
            for (int r = 0; r < 4; ++r) O[ft][r] *= c[r];
        }

        // PV: O[q][f] += P[q][s] V[s][f]
#pragma unroll
        for (int ks = 0; ks < 2; ++ks) {
            s16x8 pf = *(const s16x8*)&Pw[n * 68 + ks * 32 + g * 8];
#pragma unroll
            for (int ft = 0; ft < 8; ++ft) {
                s16x8 vf = *(const s16x8*)&Vs[(ft * 16 + n) * 72 + ks * 32 + g * 8];
                O[ft] = __builtin_amdgcn_mfma_f32_16x16x32_bf16(pf, vf, O[ft], 0, 0, 0);
            }
        }
    }

    // epilogue: normalize, residual-gate, store
    float rinv[4];
#pragma unroll
    for (int r = 0; r < 4; ++r) rinv[r] = 1.f / lsum[r];
#pragma unroll
    for (int ft = 0; ft < 8; ++ft) {
        int f = ft * 16 + n;
#pragma unroll
        for (int r = 0; r < 4; ++r) {
            int q = q0 + g * 4 + r;
            float val = O[ft][r] * rinv[r];
            float xv = orig[bso * b + (size_t)f * cso + (size_t)q * tso];
            float res = val * xv + xv;
            out_tf[((size_t)b * TT + q) * FF + f] = res;
            out_x[((size_t)b * TP + xoff + q) * FF + f] = f2bf(res);
        }
    }
}

// ---------------------------------------------------------------------------
// MMD partials per timepoint (fp32 exact).
// ---------------------------------------------------------------------------
__global__ __launch_bounds__(256) void mmd_kernel(
    const float* __restrict__ f1, const float* __restrict__ f2,
    float* __restrict__ partials)
{
    int t = blockIdx.x;
    __shared__ float v1[32][129], v2[32][129];
    __shared__ float red[256];
    int tid = threadIdx.x;
    for (int l = tid; l < 4096; l += 256) {
        int i = l >> 7, f = l & 127;
        v1[i][f] = f1[((size_t)i * TT + t) * FF + f];
        v2[i][f] = f2[((size_t)i * TT + t) * FF + f];
    }
    __syncthreads();
    float s = 0.f;
    for (int r = 0; r < 4; ++r) {
        int p = tid + 256 * r;
        int i = p >> 5, j = p & 31;
        float dxx = 0.f, dyy = 0.f, dxy = 0.f;
        for (int f = 0; f < 128; ++f) {
            float a = v1[i][f], b_ = v1[j][f], c = v2[i][f], d = v2[j][f];
            float e1 = a - b_, e2 = c - d, e3 = a - d;
            dxx += e1 * e1; dyy += e2 * e2; dxy += e3 * e3;
        }
        s += __expf(-0.5f * dxx) + __expf(-0.5f * dyy) - 2.f * __expf(-0.5f * dxy);
    }
    red[tid] = s;
    __syncthreads();
    for (int off = 128; off; off >>= 1) {
        if (tid < off) red[tid] += red[tid + off];
        __syncthreads();
    }
    if (tid == 0) partials[t] = red[0];
}

// ---------------------------------------------------------------------------
// weight prep: w4[plane][o][c] bf16, planes 0..2 = conv taps, 3 = residual.
// ---------------------------------------------------------------------------
__global__ __launch_bounds__(256) void prep_w_kernel(
    const float* __restrict__ cw, const float* __restrict__ rw,
    unsigned short* __restrict__ out, int Cin)
{
    int idx = blockIdx.x * 256 + threadIdx.x;
    int total = 4 * 256 * Cin;
    if (idx >= total) return;
    int p = idx / (256 * Cin);
    int rem = idx - p * 256 * Cin;
    int o = rem / Cin, c = rem - o * Cin;
    float v = (p < 3) ? cw[(o * Cin + c) * 3 + p] : rw[o * Cin + c];
    out[idx] = f2bf(v);
}

// ---------------------------------------------------------------------------
// TCN layer via MFMA.  x bf16 [b][t][Cin]; w4 bf16 [4][256][Cin];
// out bf16 [b][t][256].  out = relu(conv + cb) + res + rb.
// grid (4, 4, 32), block 256 (4 waves); wave tile 64o x 64t.
// ---------------------------------------------------------------------------
__global__ __launch_bounds__(256) void tcn_mfma_kernel(
    const unsigned short* __restrict__ x, int Cin, int d,
    const unsigned short* __restrict__ w4,
    const float* __restrict__ cb, const float* __restrict__ rb,
    unsigned short* __restrict__ out)
{
    int t0 = blockIdx.x * 256, o0 = blockIdx.y * 64, b = blockIdx.z;
    __shared__ __align__(16) unsigned short xs[264 * 40];
    int tid = threadIdx.x;
    int wid = tid >> 6, lane = tid & 63;
    int n = lane & 15, g = lane >> 4;
    int wt0 = wid * 64;
    int d2 = 2 * d;
    int nrow = 256 + d2;
    const unsigned short* xb = x + (size_t)b * TP * Cin;

    f32x4 accc[4][4], accr[4][4];
#pragma unroll
    for (int i = 0; i < 4; ++i)
#pragma unroll
        for (int j = 0; j < 4; ++j) {
            accc[i][j] = (f32x4){0.f, 0.f, 0.f, 0.f};
            accr[i][j] = (f32x4){0.f, 0.f, 0.f, 0.f};
        }

    for (int c0 = 0; c0 < Cin; c0 += 32) {
        __syncthreads();
        for (int l = tid; l < nrow * 4; l += 256) {
            int row = l >> 2, gg = l & 3;
            int tg = t0 - d2 + row;
            u16x8 v = {0, 0, 0, 0, 0, 0, 0, 0};
            if (tg >= 0 && tg < TP)
                v = *(const u16x8*)&xb[(size_t)tg * Cin + c0 + gg * 8];
            *(u16x8*)&xs[row * 40 + gg * 8] = v;
        }
        __syncthreads();
        s16x8 bf[3][4];
#pragma unroll
        for (int j = 0; j < 4; ++j)
#pragma unroll
            for (int k = 0; k < 3; ++k)
                bf[k][j] = *(const s16x8*)&xs[(wt0 + j * 16 + n + k * d) * 40 + g * 8];
#pragma unroll
        for (int i = 0; i < 4; ++i) {
            const unsigned short* wb = &w4[(size_t)(o0 + i * 16 + n) * Cin + c0 + g * 8];
            size_t ps = (size_t)256 * Cin;
            s16x8 a0 = *(const s16x8*)&wb[0];
            s16x8 a1 = *(const s16x8*)&wb[ps];
            s16x8 a2 = *(const s16x8*)&wb[2 * ps];
            s16x8 ar = *(const s16x8*)&wb[3 * ps];
#pragma unroll
            for (int j = 0; j < 4; ++j) {
                accc[i][j] = __builtin_amdgcn_mfma_f32_16x16x32_bf16(a0, bf[0][j], accc[i][j], 0, 0, 0);
                accc[i][j] = __builtin_amdgcn_mfma_f32_16x16x32_bf16(a1, bf[1][j], accc[i][j], 0, 0, 0);
                accc[i][j] = __builtin_amdgcn_mfma_f32_16x16x32_bf16(a2, bf[2][j], accc[i][j], 0, 0, 0);
                accr[i][j] = __builtin_amdgcn_mfma_f32_16x16x32_bf16(ar, bf[2][j], accr[i][j], 0, 0, 0);
            }
        }
    }
#pragma unroll
    for (int i = 0; i < 4; ++i) {
        int ob = o0 + i * 16 + g * 4;
        float c0b = cb[ob], c1b = cb[ob + 1], c2b = cb[ob + 2], c3b = cb[ob + 3];
        float r0b = rb[ob], r1b = rb[ob + 1], r2b = rb[ob + 2], r3b = rb[ob + 3];
#pragma unroll
        for (int j = 0; j < 4; ++j) {
            int t = t0 + wt0 + j * 16 + n;
            u16x4 pk;
            pk[0] = f2bf(fmaxf(accc[i][j][0] + c0b, 0.f) + accr[i][j][0] + r0b);
            pk[1] = f2bf(fmaxf(accc[i][j][1] + c1b, 0.f) + accr[i][j][1] + r1b);
            pk[2] = f2bf(fmaxf(accc[i][j][2] + c2b, 0.f) + accr[i][j][2] + r2b);
            pk[3] = f2bf(fmaxf(accc[i][j][3] + c3b, 0.f) + accr[i][j][3] + r3b);
            *(u16x4*)&out[((size_t)b * TP + t) * HID + ob] = pk;
        }
    }
}

// ---------------------------------------------------------------------------
// pool partials: block (tslice, b); thread = channel; sum 256 t.
// ---------------------------------------------------------------------------
__global__ __launch_bounds__(256) void pool_kernel(
    const unsigned short* __restrict__ h, float* __restrict__ pp)
{
    int ts = blockIdx.x, b = blockIdx.y;
    int c = threadIdx.x;
    const unsigned short* base = h + ((size_t)b * TP + ts * 256) * HID + c;
    float s = 0.f;
    for (int t = 0; t < 256; ++t) s += bf2f(base[(size_t)t * HID]);
    pp[(b * 4 + ts) * HID + c] = s;
}

// ---------------------------------------------------------------------------
// final: fc on pooled means + MMD reduce.
// ---------------------------------------------------------------------------
__global__ __launch_bounds__(256) void final_kernel(
    const float* __restrict__ pp, const float* __restrict__ fcw,
    const float* __restrict__ fcb, const float* __restrict__ partials,
    float* __restrict__ dout)
{
    int tid = threadIdx.x;
    if (tid < 128) {
        int b = tid >> 2, k = tid & 3;
        float s = 0.f;
        for (int c = 0; c < HID; ++c) {
            float pc = pp[(b * 4 + 0) * HID + c] + pp[(b * 4 + 1) * HID + c]
                     + pp[(b * 4 + 2) * HID + c] + pp[(b * 4 + 3) * HID + c];
            s += pc * fcw[k * HID + c];
        }
        dout[tid] = fcb[k] + s * (1.f / 1024.f);
    } else if (tid < 192) {
        int lane = tid - 128;
        float s = 0.f;
        for (int j = 0; j < 8; ++j) s += partials[lane + 64 * j];
        for (int off = 32; off; off >>= 1) s += __shfl_down(s, off);
        if (lane == 0) dout[128] = s * (1.f / (32.f * 32.f * 512.f));
    }
}

// ---------------------------------------------------------------------------
extern "C" void kernel_launch(void* const* d_in, const int* in_sizes, int n_in,
                              void* d_out, int out_size, void* d_ws, size_t ws_size,
                              hipStream_t stream)
{
    const float* feat1 = (const float*)d_in[0];
    const float* feat2 = (const float*)d_in[1];
    const float* wq_a = (const float*)d_in[2];
    const float* bq_a = (const float*)d_in[3];
    const float* wk_a = (const float*)d_in[4];
    const float* bk_a = (const float*)d_in[5];
    const float* wv_a = (const float*)d_in[6];
    const float* bv_a = (const float*)d_in[7];
    const float* wq_b = (const float*)d_in[8];
    const float* bq_b = (const float*)d_in[9];
    const float* wk_b = (const float*)d_in[10];
    const float* bk_b = (const float*)d_in[11];
    const float* wv_b = (const float*)d_in[12];
    const float* bv_b = (const float*)d_in[13];
    const float* cw0 = (const float*)d_in[14];
    const float* cb0 = (const float*)d_in[15];
    const float* rw0 = (const float*)d_in[16];
    const float* rb0 = (const float*)d_in[17];
    const float* cw1 = (const float*)d_in[18];
    const float* cb1 = (const float*)d_in[19];
    const float* rw1 = (const float*)d_in[20];
    const float* rb1 = (const float*)d_in[21];
    const float* cw2 = (const float*)d_in[22];
    const float* cb2 = (const float*)d_in[23];
    const float* rw2 = (const float*)d_in[24];
    const float* rb2 = (const float*)d_in[25];
    const float* fcw = (const float*)d_in[26];
    const float* fcb = (const float*)d_in[27];
    float* dout = (float*)d_out;

    // workspace layout (float offsets):
    //   Qbf  @ 0        (bf16 [32][512][128] = 1048576 floats)
    //   Kbf  @ 1048576
    //   Vt   @ 2097152  (bf16 [32][128][512])
    //   f1tf @ 3145728  (fp32 [32][512][128] = 2097152 floats)
    //   f2tf @ 5242880
    //   xbuf @ 7340032  (bf16 [32][1024][128] = 2097152 floats)
    //   wbuf @ 9437184  (bf16, 655360 u16 = 327680 floats)
    //   poolpart @ 9764864 (32768), mmdpart @ 9797632 (512)
    //   h_a (bf16 [32][1024][256] = 4194304 floats) aliases 0..4194304
    //     (Q/K/Vt/f1tf dead after mmd+qkvB)
    //   h_b aliases 4194304..8388608 (f2tf/xbuf dead by TCN L1)
    float* ws = (float*)d_ws;
    unsigned short* Qbf = (unsigned short*)ws;
    unsigned short* Kbf = (unsigned short*)(ws + 1048576);
    unsigned short* Vt  = (unsigned short*)(ws + 2097152);
    float* f1tf = ws + 3145728;
    float* f2tf = ws + 5242880;
    unsigned short* xbuf = (unsigned short*)(ws + 7340032);
    unsigned short* wbuf = (unsigned short*)(ws + 9437184);
    unsigned short* wb0 = wbuf;
    unsigned short* wb1 = wbuf + 131072;
    unsigned short* wb2 = wbuf + 393216;
    float* poolpart = ws + 9764864;
    float* mmdpart  = ws + 9797632;
    unsigned short* h_a = (unsigned short*)ws;
    unsigned short* h_b = (unsigned short*)(ws + 4194304);

    // branch A: Q from feat2, K/V from feat1 ([B][F][1][T]: cs=512, ts=1)
    qkv_kernel<<<dim3(2, 16, 32), 256, 0, stream>>>(
        feat2, 65536LL, 512, 1, feat1, 65536LL, 512, 1,
        wq_a, bq_a, wk_a, bk_a, wv_a, bv_a, Qbf, Kbf, Vt);
    attn_mfma_kernel<<<dim3(8, 32), 256, 0, stream>>>(
        Qbf, Kbf, Vt, feat1, 65536LL, 512, 1, f1tf, xbuf, 0);

    // branch B: Q from updated f1 (f1tf [B][T][F]: cs=1, ts=128), K/V from feat2
    qkv_kernel<<<dim3(2, 16, 32), 256, 0, stream>>>(
        f1tf, 65536LL, 1, 128, feat2, 65536LL, 512, 1,
        wq_b, bq_b, wk_b, bk_b, wv_b, bv_b, Qbf, Kbf, Vt);
    attn_mfma_kernel<<<dim3(8, 32), 256, 0, stream>>>(
        Qbf, Kbf, Vt, feat2, 65536LL, 512, 1, f2tf, xbuf, 512);

    // MMD partials (before TCN overwrites f1tf/f2tf regions)
    mmd_kernel<<<dim3(512), 256, 0, stream>>>(f1tf, f2tf, mmdpart);

    // weight prep (bf16 planes)
    prep_w_kernel<<<dim3(512), 256, 0, stream>>>(cw0, rw0, wb0, 128);
    prep_w_kernel<<<dim3(1024), 256, 0, stream>>>(cw1, rw1, wb1, 256);
    prep_w_kernel<<<dim3(1024), 256, 0, stream>>>(cw2, rw2, wb2, 256);

    // TCN stack: xbuf(128ch) -> h_a -> h_b -> h_a
    tcn_mfma_kernel<<<dim3(4, 4, 32), 256, 0, stream>>>(xbuf, 128, 1, wb0, cb0, rb0, h_a);
    tcn_mfma_kernel<<<dim3(4, 4, 32), 256, 0, stream>>>(h_a, 256, 2, wb1, cb1, rb1, h_b);
    tcn_mfma_kernel<<<dim3(4, 4, 32), 256, 0, stream>>>(h_b, 256, 4, wb2, cb2, rb2, h_a);

    pool_kernel<<<dim3(4, 32), 256, 0, stream>>>(h_a, poolpart);
    final_kernel<<<dim3(1), 256, 0, stream>>>(poolpart, fcw, fcb, mmdpart, dout);
}

// Round 4
// 305.709 us; speedup vs baseline: 5.0963x; 1.4068x over previous
//
#include <hip/hip_runtime.h>

#define BB 32
#define TT 512
#define FF 128
#define HID 256
#define TP 1024

typedef __attribute__((ext_vector_type(8))) short s16x8;
typedef __attribute__((ext_vector_type(8))) unsigned short u16x8;
typedef __attribute__((ext_vector_type(4))) unsigned short u16x4;
typedef __attribute__((ext_vector_type(4))) float f32x4;

static __device__ __forceinline__ unsigned short f2bf(float f) {
    unsigned u = __builtin_bit_cast(unsigned, f);
    u = (u + 0x7FFFu + ((u >> 16) & 1u)) >> 16;
    return (unsigned short)u;
}
static __device__ __forceinline__ float bf2f(unsigned short b) {
    return __builtin_bit_cast(float, ((unsigned)b) << 16);
}

// ---------------------------------------------------------------------------
// transpose-convert: src fp32 [b][128][512] -> dst bf16 [b][512][128].
// grid (16, 4, 32), block 256.
// ---------------------------------------------------------------------------
__global__ __launch_bounds__(256) void t2bf_kernel(
    const float* __restrict__ src, unsigned short* __restrict__ dst)
{
    int t0 = blockIdx.x * 32, c0 = blockIdx.y * 32, b = blockIdx.z;
    __shared__ float tile[32][33];
    int tid = threadIdx.x;
    for (int l = tid; l < 1024; l += 256) {
        int c = l >> 5, t = l & 31;
        tile[c][t] = src[((size_t)b * FF + c0 + c) * TT + t0 + t];
    }
    __syncthreads();
    for (int l = tid; l < 1024; l += 256) {
        int t = l >> 5, c = l & 31;
        dst[((size_t)b * TT + t0 + t) * FF + c0 + c] = f2bf(tile[c][t]);
    }
}

// ---------------------------------------------------------------------------
// QKV weight prep: out bf16 [6][128][128]; planes 0,3 (wq_a, wq_b) pre-scaled.
// grid (384), block 256.
// ---------------------------------------------------------------------------
__global__ __launch_bounds__(256) void prep_qkvw_kernel(
    const float* __restrict__ wqa, const float* __restrict__ wka,
    const float* __restrict__ wva, const float* __restrict__ wqb,
    const float* __restrict__ wkb, const float* __restrict__ wvb,
    unsigned short* __restrict__ out)
{
    int idx = blockIdx.x * 256 + threadIdx.x;
    if (idx >= 6 * 16384) return;
    int p = idx >> 14, rc = idx & 16383;
    const float* srcs[6] = {wqa, wka, wva, wqb, wkb, wvb};
    float v = srcs[p][rc];
    if (p == 0 || p == 3) v *= 0.088388347648318447f;
    out[idx] = f2bf(v);
}

// ---------------------------------------------------------------------------
// QKV projection via MFMA.  xq/xkv bf16 [*][t][128] (row stride 128, batch
// stride passed).  w3 bf16 [3][128][128] (plane 0 pre-scaled).  Outputs:
// Qo bf16 [B][T][F] (scaled), Ko bf16 [B][T][F], Vt bf16 [B][F][T].
// grid (16, 32), block 256 = 4 waves; wave = 16t x 64f x 3proj.
// ---------------------------------------------------------------------------
__global__ __launch_bounds__(256) void proj_mfma_kernel(
    const unsigned short* __restrict__ xq_src, long long xq_bs,
    const unsigned short* __restrict__ xkv_src, long long xkv_bs,
    const unsigned short* __restrict__ w3,
    const float* __restrict__ bq, const float* __restrict__ bk,
    const float* __restrict__ bv,
    unsigned short* __restrict__ Qo, unsigned short* __restrict__ Ko,
    unsigned short* __restrict__ Vt)
{
    int t0 = blockIdx.x * 32, b = blockIdx.y;
    __shared__ __align__(16) unsigned short xsq[32 * 136];
    __shared__ __align__(16) unsigned short xskv[32 * 136];
    int tid = threadIdx.x;
    int wid = tid >> 6, lane = tid & 63;
    int n = lane & 15, g = lane >> 4;
    int tsub = (wid & 1) * 16, fh = (wid >> 1) * 64;

    for (int l = tid; l < 512; l += 256) {
        int r = l >> 4, cc = l & 15;
        *(u16x8*)&xsq[r * 136 + cc * 8] =
            *(const u16x8*)&xq_src[xq_bs * b + (size_t)(t0 + r) * FF + cc * 8];
        *(u16x8*)&xskv[r * 136 + cc * 8] =
            *(const u16x8*)&xkv_src[xkv_bs * b + (size_t)(t0 + r) * FF + cc * 8];
    }
    __syncthreads();

    f32x4 acc[3][4];
#pragma unroll
    for (int p = 0; p < 3; ++p)
#pragma unroll
        for (int i = 0; i < 4; ++i) acc[p][i] = (f32x4){0.f, 0.f, 0.f, 0.f};

#pragma unroll
    for (int kk = 0; kk < 4; ++kk) {
        s16x8 bxq = *(const s16x8*)&xsq[(tsub + n) * 136 + kk * 32 + g * 8];
        s16x8 bxkv = *(const s16x8*)&xskv[(tsub + n) * 136 + kk * 32 + g * 8];
#pragma unroll
        for (int i = 0; i < 4; ++i) {
            const unsigned short* wb = &w3[(size_t)(fh + i * 16 + n) * 128 + kk * 32 + g * 8];
            s16x8 a0 = *(const s16x8*)&wb[0];
            s16x8 a1 = *(const s16x8*)&wb[16384];
            s16x8 a2 = *(const s16x8*)&wb[32768];
            acc[0][i] = __builtin_amdgcn_mfma_f32_16x16x32_bf16(a0, bxq, acc[0][i], 0, 0, 0);
            acc[1][i] = __builtin_amdgcn_mfma_f32_16x16x32_bf16(a1, bxkv, acc[1][i], 0, 0, 0);
            acc[2][i] = __builtin_amdgcn_mfma_f32_16x16x32_bf16(a2, bxkv, acc[2][i], 0, 0, 0);
        }
    }

    const float scale = 0.088388347648318447f;
    int t = t0 + tsub + n;
#pragma unroll
    for (int i = 0; i < 4; ++i) {
        int fb = fh + i * 16 + g * 4;
        u16x4 pk;
#pragma unroll
        for (int r = 0; r < 4; ++r) pk[r] = f2bf(acc[0][i][r] + bq[fb + r] * scale);
        *(u16x4*)&Qo[((size_t)b * TT + t) * FF + fb] = pk;
#pragma unroll
        for (int r = 0; r < 4; ++r) pk[r] = f2bf(acc[1][i][r] + bk[fb + r]);
        *(u16x4*)&Ko[((size_t)b * TT + t) * FF + fb] = pk;
#pragma unroll
        for (int r = 0; r < 4; ++r)
            Vt[((size_t)b * FF + fb + r) * TT + t] = f2bf(acc[2][i][r] + bv[fb + r]);
    }
}

// ---------------------------------------------------------------------------
// Flash attention via MFMA.  Q bf16 [B][T][F] (pre-scaled), K bf16 [B][T][F],
// Vt bf16 [B][F][T].  out = attn*orig + orig -> out_tf fp32 [B][T][F] and
// out_x bf16 [b][t][c] at row offset xoff.
// grid (8 q-tiles, 32 b), block 256 = 4 waves; wave owns 16 q-rows.
// ---------------------------------------------------------------------------
__global__ __launch_bounds__(256) void attn_mfma_kernel(
    const unsigned short* __restrict__ Qb, const unsigned short* __restrict__ Kb,
    const unsigned short* __restrict__ Vtb,
    const float* __restrict__ orig, long long bso, int cso, int tso,
    float* __restrict__ out_tf, unsigned short* __restrict__ out_x, int xoff)
{
    __shared__ __align__(16) unsigned short Ks[64 * 136];   // [s][f] pitch 136
    __shared__ __align__(16) unsigned short Vs[128 * 72];   // [f][s] pitch 72
    __shared__ __align__(16) unsigned short Ps[4 * 16 * 68];// per-wave [q][s] pitch 68

    int t0 = blockIdx.x * 64, b = blockIdx.y;
    int tid = threadIdx.x;
    int wid = tid >> 6, lane = tid & 63;
    int n = lane & 15, g = lane >> 4;
    int q0 = t0 + wid * 16;
    unsigned short* Pw = &Ps[wid * 1088];

    s16x8 qf[4];
#pragma unroll
    for (int kk = 0; kk < 4; ++kk)
        qf[kk] = *(const s16x8*)&Qb[((size_t)b * TT + q0 + n) * FF + kk * 32 + g * 8];

    u16x8 kst[4], vst[4];
#pragma unroll
    for (int ii = 0; ii < 4; ++ii) {
        int l = tid + 256 * ii;
        kst[ii] = *(const u16x8*)&Kb[((size_t)b * TT + (l >> 4)) * FF + (l & 15) * 8];
        vst[ii] = *(const u16x8*)&Vtb[((size_t)b * FF + (l >> 3)) * TT + (l & 7) * 8];
    }

    f32x4 O[8];
#pragma unroll
    for (int ft = 0; ft < 8; ++ft) O[ft] = (f32x4){0.f, 0.f, 0.f, 0.f};
    float m[4] = {-1e30f, -1e30f, -1e30f, -1e30f};
    float lsum[4] = {0.f, 0.f, 0.f, 0.f};

    for (int it = 0; it < 8; ++it) {
        __syncthreads();
#pragma unroll
        for (int ii = 0; ii < 4; ++ii) {
            int l = tid + 256 * ii;
            *(u16x8*)&Ks[(l >> 4) * 136 + (l & 15) * 8] = kst[ii];
            *(u16x8*)&Vs[(l >> 3) * 72 + (l & 7) * 8] = vst[ii];
        }
        __syncthreads();
        if (it < 7) {
            int s0n = (it + 1) * 64;
#pragma unroll
            for (int ii = 0; ii < 4; ++ii) {
                int l = tid + 256 * ii;
                kst[ii] = *(const u16x8*)&Kb[((size_t)b * TT + s0n + (l >> 4)) * FF + (l & 15) * 8];
                vst[ii] = *(const u16x8*)&Vtb[((size_t)b * FF + (l >> 3)) * TT + s0n + (l & 7) * 8];
            }
        }

        f32x4 acc[4];
#pragma unroll
        for (int st = 0; st < 4; ++st) acc[st] = (f32x4){0.f, 0.f, 0.f, 0.f};
#pragma unroll
        for (int kk = 0; kk < 4; ++kk) {
#pragma unroll
            for (int st = 0; st < 4; ++st) {
                s16x8 kf = *(const s16x8*)&Ks[(st * 16 + n) * 136 + kk * 32 + g * 8];
                acc[st] = __builtin_amdgcn_mfma_f32_16x16x32_bf16(qf[kk], kf, acc[st], 0, 0, 0);
            }
        }

        float mnew[4], c[4], rs[4];
#pragma unroll
        for (int r = 0; r < 4; ++r) {
            float tm = fmaxf(fmaxf(acc[0][r], acc[1][r]), fmaxf(acc[2][r], acc[3][r]));
#pragma unroll
            for (int msk = 1; msk < 16; msk <<= 1) tm = fmaxf(tm, __shfl_xor(tm, msk));
            mnew[r] = fmaxf(m[r], tm);
            c[r] = __expf(m[r] - mnew[r]);
            m[r] = mnew[r];
            rs[r] = 0.f;
        }
#pragma unroll
        for (int st = 0; st < 4; ++st) {
#pragma unroll
            for (int r = 0; r < 4; ++r) {
                float p = __expf(acc[st][r] - mnew[r]);
                rs[r] += p;
                Pw[(g * 4 + r) * 68 + st * 16 + n] = f2bf(p);
            }
        }
#pragma unroll
        for (int r = 0; r < 4; ++r) {
#pragma unroll
            for (int msk = 1; msk < 16; msk <<= 1) rs[r] += __shfl_xor(rs[r], msk);
            lsum[r] = lsum[r] * c[r] + rs[r];
        }
#pragma unroll
        for (int ft = 0; ft < 8; ++ft) {
#pragma unroll
            for (int r = 0; r < 4; ++r) O[ft][r] *= c[r];
        }

#pragma unroll
        for (int ks = 0; ks < 2; ++ks) {
            s16x8 pf = *(const s16x8*)&Pw[n * 68 + ks * 32 + g * 8];
#pragma unroll
            for (int ft = 0; ft < 8; ++ft) {
                s16x8 vf = *(const s16x8*)&Vs[(ft * 16 + n) * 72 + ks * 32 + g * 8];
                O[ft] = __builtin_amdgcn_mfma_f32_16x16x32_bf16(pf, vf, O[ft], 0, 0, 0);
            }
        }
    }

    float rinv[4];
#pragma unroll
    for (int r = 0; r < 4; ++r) rinv[r] = 1.f / lsum[r];
#pragma unroll
    for (int ft = 0; ft < 8; ++ft) {
        int f = ft * 16 + n;
#pragma unroll
        for (int r = 0; r < 4; ++r) {
            int q = q0 + g * 4 + r;
            float val = O[ft][r] * rinv[r];
            float xv = orig[bso * b + (size_t)f * cso + (size_t)q * tso];
            float res = val * xv + xv;
            out_tf[((size_t)b * TT + q) * FF + f] = res;
            out_x[((size_t)b * TP + xoff + q) * FF + f] = f2bf(res);
        }
    }
}

// ---------------------------------------------------------------------------
// MMD partials per timepoint (fp32 exact).
// ---------------------------------------------------------------------------
__global__ __launch_bounds__(256) void mmd_kernel(
    const float* __restrict__ f1, const float* __restrict__ f2,
    float* __restrict__ partials)
{
    int t = blockIdx.x;
    __shared__ float v1[32][129], v2[32][129];
    __shared__ float red[256];
    int tid = threadIdx.x;
    for (int l = tid; l < 4096; l += 256) {
        int i = l >> 7, f = l & 127;
        v1[i][f] = f1[((size_t)i * TT + t) * FF + f];
        v2[i][f] = f2[((size_t)i * TT + t) * FF + f];
    }
    __syncthreads();
    float s = 0.f;
    for (int r = 0; r < 4; ++r) {
        int p = tid + 256 * r;
        int i = p >> 5, j = p & 31;
        float dxx = 0.f, dyy = 0.f, dxy = 0.f;
        for (int f = 0; f < 128; ++f) {
            float a = v1[i][f], b_ = v1[j][f], c = v2[i][f], d = v2[j][f];
            float e1 = a - b_, e2 = c - d, e3 = a - d;
            dxx += e1 * e1; dyy += e2 * e2; dxy += e3 * e3;
        }
        s += __expf(-0.5f * dxx) + __expf(-0.5f * dyy) - 2.f * __expf(-0.5f * dxy);
    }
    red[tid] = s;
    __syncthreads();
    for (int off = 128; off; off >>= 1) {
        if (tid < off) red[tid] += red[tid + off];
        __syncthreads();
    }
    if (tid == 0) partials[t] = red[0];
}

// ---------------------------------------------------------------------------
// TCN weight prep: w4[plane][o][c] bf16, planes 0..2 = conv taps, 3 = residual.
// ---------------------------------------------------------------------------
__global__ __launch_bounds__(256) void prep_w_kernel(
    const float* __restrict__ cw, const float* __restrict__ rw,
    unsigned short* __restrict__ out, int Cin)
{
    int idx = blockIdx.x * 256 + threadIdx.x;
    int total = 4 * 256 * Cin;
    if (idx >= total) return;
    int p = idx / (256 * Cin);
    int rem = idx - p * 256 * Cin;
    int o = rem / Cin, c = rem - o * Cin;
    float v = (p < 3) ? cw[(o * Cin + c) * 3 + p] : rw[o * Cin + c];
    out[idx] = f2bf(v);
}

// ---------------------------------------------------------------------------
// TCN layer via MFMA.  x bf16 [b][t][Cin]; w4 bf16 [4][256][Cin];
// out bf16 [b][t][256].  grid (4, 4, 32), block 256 (4 waves).
// ---------------------------------------------------------------------------
__global__ __launch_bounds__(256) void tcn_mfma_kernel(
    const unsigned short* __restrict__ x, int Cin, int d,
    const unsigned short* __restrict__ w4,
    const float* __restrict__ cb, const float* __restrict__ rb,
    unsigned short* __restrict__ out)
{
    int t0 = blockIdx.x * 256, o0 = blockIdx.y * 64, b = blockIdx.z;
    __shared__ __align__(16) unsigned short xs[264 * 40];
    int tid = threadIdx.x;
    int wid = tid >> 6, lane = tid & 63;
    int n = lane & 15, g = lane >> 4;
    int wt0 = wid * 64;
    int d2 = 2 * d;
    int nrow = 256 + d2;
    const unsigned short* xb = x + (size_t)b * TP * Cin;

    f32x4 accc[4][4], accr[4][4];
#pragma unroll
    for (int i = 0; i < 4; ++i)
#pragma unroll
        for (int j = 0; j < 4; ++j) {
            accc[i][j] = (f32x4){0.f, 0.f, 0.f, 0.f};
            accr[i][j] = (f32x4){0.f, 0.f, 0.f, 0.f};
        }

    for (int c0 = 0; c0 < Cin; c0 += 32) {
        __syncthreads();
        for (int l = tid; l < nrow * 4; l += 256) {
            int row = l >> 2, gg = l & 3;
            int tg = t0 - d2 + row;
            u16x8 v = {0, 0, 0, 0, 0, 0, 0, 0};
            if (tg >= 0 && tg < TP)
                v = *(const u16x8*)&xb[(size_t)tg * Cin + c0 + gg * 8];
            *(u16x8*)&xs[row * 40 + gg * 8] = v;
        }
        __syncthreads();
        s16x8 bf[3][4];
#pragma unroll
        for (int j = 0; j < 4; ++j)
#pragma unroll
            for (int k = 0; k < 3; ++k)
                bf[k][j] = *(const s16x8*)&xs[(wt0 + j * 16 + n + k * d) * 40 + g * 8];
#pragma unroll
        for (int i = 0; i < 4; ++i) {
            const unsigned short* wb = &w4[(size_t)(o0 + i * 16 + n) * Cin + c0 + g * 8];
            size_t ps = (size_t)256 * Cin;
            s16x8 a0 = *(const s16x8*)&wb[0];
            s16x8 a1 = *(const s16x8*)&wb[ps];
            s16x8 a2 = *(const s16x8*)&wb[2 * ps];
            s16x8 ar = *(const s16x8*)&wb[3 * ps];
#pragma unroll
            for (int j = 0; j < 4; ++j) {
                accc[i][j] = __builtin_amdgcn_mfma_f32_16x16x32_bf16(a0, bf[0][j], accc[i][j], 0, 0, 0);
                accc[i][j] = __builtin_amdgcn_mfma_f32_16x16x32_bf16(a1, bf[1][j], accc[i][j], 0, 0, 0);
                accc[i][j] = __builtin_amdgcn_mfma_f32_16x16x32_bf16(a2, bf[2][j], accc[i][j], 0, 0, 0);
                accr[i][j] = __builtin_amdgcn_mfma_f32_16x16x32_bf16(ar, bf[2][j], accr[i][j], 0, 0, 0);
            }
        }
    }
#pragma unroll
    for (int i = 0; i < 4; ++i) {
        int ob = o0 + i * 16 + g * 4;
        float c0b = cb[ob], c1b = cb[ob + 1], c2b = cb[ob + 2], c3b = cb[ob + 3];
        float r0b = rb[ob], r1b = rb[ob + 1], r2b = rb[ob + 2], r3b = rb[ob + 3];
#pragma unroll
        for (int j = 0; j < 4; ++j) {
            int t = t0 + wt0 + j * 16 + n;
            u16x4 pk;
            pk[0] = f2bf(fmaxf(accc[i][j][0] + c0b, 0.f) + accr[i][j][0] + r0b);
            pk[1] = f2bf(fmaxf(accc[i][j][1] + c1b, 0.f) + accr[i][j][1] + r1b);
            pk[2] = f2bf(fmaxf(accc[i][j][2] + c2b, 0.f) + accr[i][j][2] + r2b);
            pk[3] = f2bf(fmaxf(accc[i][j][3] + c3b, 0.f) + accr[i][j][3] + r3b);
            *(u16x4*)&out[((size_t)b * TP + t) * HID + ob] = pk;
        }
    }
}

// ---------------------------------------------------------------------------
// pool partials: block (tslice, b); thread = channel; sum 256 t.
// ---------------------------------------------------------------------------
__global__ __launch_bounds__(256) void pool_kernel(
    const unsigned short* __restrict__ h, float* __restrict__ pp)
{
    int ts = blockIdx.x, b = blockIdx.y;
    int c = threadIdx.x;
    const unsigned short* base = h + ((size_t)b * TP + ts * 256) * HID + c;
    float s = 0.f;
    for (int t = 0; t < 256; ++t) s += bf2f(base[(size_t)t * HID]);
    pp[(b * 4 + ts) * HID + c] = s;
}

// ---------------------------------------------------------------------------
// final: fc on pooled means + MMD reduce.
// ---------------------------------------------------------------------------
__global__ __launch_bounds__(256) void final_kernel(
    const float* __restrict__ pp, const float* __restrict__ fcw,
    const float* __restrict__ fcb, const float* __restrict__ partials,
    float* __restrict__ dout)
{
    int tid = threadIdx.x;
    if (tid < 128) {
        int b = tid >> 2, k = tid & 3;
        float s = 0.f;
        for (int c = 0; c < HID; ++c) {
            float pc = pp[(b * 4 + 0) * HID + c] + pp[(b * 4 + 1) * HID + c]
                     + pp[(b * 4 + 2) * HID + c] + pp[(b * 4 + 3) * HID + c];
            s += pc * fcw[k * HID + c];
        }
        dout[tid] = fcb[k] + s * (1.f / 1024.f);
    } else if (tid < 192) {
        int lane = tid - 128;
        float s = 0.f;
        for (int j = 0; j < 8; ++j) s += partials[lane + 64 * j];
        for (int off = 32; off; off >>= 1) s += __shfl_down(s, off);
        if (lane == 0) dout[128] = s * (1.f / (32.f * 32.f * 512.f));
    }
}

// ---------------------------------------------------------------------------
extern "C" void kernel_launch(void* const* d_in, const int* in_sizes, int n_in,
                              void* d_out, int out_size, void* d_ws, size_t ws_size,
                              hipStream_t stream)
{
    const float* feat1 = (const float*)d_in[0];
    const float* feat2 = (const float*)d_in[1];
    const float* wq_a = (const float*)d_in[2];
    const float* bq_a = (const float*)d_in[3];
    const float* wk_a = (const float*)d_in[4];
    const float* bk_a = (const float*)d_in[5];
    const float* wv_a = (const float*)d_in[6];
    const float* bv_a = (const float*)d_in[7];
    const float* wq_b = (const float*)d_in[8];
    const float* bq_b = (const float*)d_in[9];
    const float* wk_b = (const float*)d_in[10];
    const float* bk_b = (const float*)d_in[11];
    const float* wv_b = (const float*)d_in[12];
    const float* bv_b = (const float*)d_in[13];
    const float* cw0 = (const float*)d_in[14];
    const float* cb0 = (const float*)d_in[15];
    const float* rw0 = (const float*)d_in[16];
    const float* rb0 = (const float*)d_in[17];
    const float* cw1 = (const float*)d_in[18];
    const float* cb1 = (const float*)d_in[19];
    const float* rw1 = (const float*)d_in[20];
    const float* rb1 = (const float*)d_in[21];
    const float* cw2 = (const float*)d_in[22];
    const float* cb2 = (const float*)d_in[23];
    const float* rw2 = (const float*)d_in[24];
    const float* rb2 = (const float*)d_in[25];
    const float* fcw = (const float*)d_in[26];
    const float* fcb = (const float*)d_in[27];
    float* dout = (float*)d_out;

    // workspace layout (float offsets):
    //   Qbf  @ 0        (bf16 [32][512][128] = 1048576 floats)
    //   Kbf  @ 1048576
    //   Vt   @ 2097152  (bf16 [32][128][512])
    //   f1tf @ 3145728  (fp32, 2097152 floats)
    //   f2tf @ 5242880
    //   xbuf @ 7340032  (bf16 [32][1024][128] = 2097152 floats)
    //   wbuf @ 9437184  (tcn bf16, 655360 u16 = 327680 floats)
    //   poolpart @ 9764864 (32768), mmdpart @ 9797632 (512)
    //   xbf1 @ 9798144 (bf16 [32][512][128] = 1048576 floats)
    //   xbf2 @ 10846720
    //   qkvw @ 11895296 (bf16 [6][128][128] = 98304 u16 = 49152 floats)
    //   h_a aliases 0..4194304 (Q/K/Vt/f1tf dead after mmd+projB)
    //   h_b aliases 4194304..8388608 (f2tf/xbuf dead by TCN L2)
    float* ws = (float*)d_ws;
    unsigned short* Qbf = (unsigned short*)ws;
    unsigned short* Kbf = (unsigned short*)(ws + 1048576);
    unsigned short* Vt  = (unsigned short*)(ws + 2097152);
    float* f1tf = ws + 3145728;
    float* f2tf = ws + 5242880;
    unsigned short* xbuf = (unsigned short*)(ws + 7340032);
    unsigned short* wbuf = (unsigned short*)(ws + 9437184);
    unsigned short* wb0 = wbuf;
    unsigned short* wb1 = wbuf + 131072;
    unsigned short* wb2 = wbuf + 393216;
    float* poolpart = ws + 9764864;
    float* mmdpart  = ws + 9797632;
    unsigned short* xbf1 = (unsigned short*)(ws + 9798144);
    unsigned short* xbf2 = (unsigned short*)(ws + 10846720);
    unsigned short* qkvw = (unsigned short*)(ws + 11895296);
    unsigned short* w3a = qkvw;
    unsigned short* w3b = qkvw + 3 * 16384;
    unsigned short* h_a = (unsigned short*)ws;
    unsigned short* h_b = (unsigned short*)(ws + 4194304);

    // prep: transpose-convert features; convert weights
    t2bf_kernel<<<dim3(16, 4, 32), 256, 0, stream>>>(feat1, xbf1);
    t2bf_kernel<<<dim3(16, 4, 32), 256, 0, stream>>>(feat2, xbf2);
    prep_qkvw_kernel<<<dim3(384), 256, 0, stream>>>(wq_a, wk_a, wv_a, wq_b, wk_b, wv_b, qkvw);
    prep_w_kernel<<<dim3(512), 256, 0, stream>>>(cw0, rw0, wb0, 128);
    prep_w_kernel<<<dim3(1024), 256, 0, stream>>>(cw1, rw1, wb1, 256);
    prep_w_kernel<<<dim3(1024), 256, 0, stream>>>(cw2, rw2, wb2, 256);

    // branch A: Q from feat2 (xbf2), K/V from feat1 (xbf1)
    proj_mfma_kernel<<<dim3(16, 32), 256, 0, stream>>>(
        xbf2, (long long)TT * FF, xbf1, (long long)TT * FF, w3a,
        bq_a, bk_a, bv_a, Qbf, Kbf, Vt);
    attn_mfma_kernel<<<dim3(8, 32), 256, 0, stream>>>(
        Qbf, Kbf, Vt, feat1, 65536LL, 512, 1, f1tf, xbuf, 0);

    // branch B: Q from updated f1 (xbuf rows 0..511), K/V from feat2 (xbf2)
    proj_mfma_kernel<<<dim3(16, 32), 256, 0, stream>>>(
        xbuf, (long long)TP * FF, xbf2, (long long)TT * FF, w3b,
        bq_b, bk_b, bv_b, Qbf, Kbf, Vt);
    attn_mfma_kernel<<<dim3(8, 32), 256, 0, stream>>>(
        Qbf, Kbf, Vt, feat2, 65536LL, 512, 1, f2tf, xbuf, 512);

    // MMD partials (before TCN overwrites f1tf/f2tf regions)
    mmd_kernel<<<dim3(512), 256, 0, stream>>>(f1tf, f2tf, mmdpart);

    // TCN stack: xbuf(128ch) -> h_a -> h_b -> h_a
    tcn_mfma_kernel<<<dim3(4, 4, 32), 256, 0, stream>>>(xbuf, 128, 1, wb0, cb0, rb0, h_a);
    tcn_mfma_kernel<<<dim3(4, 4, 32), 256, 0, stream>>>(h_a, 256, 2, wb1, cb1, rb1, h_b);
    tcn_mfma_kernel<<<dim3(4, 4, 32), 256, 0, stream>>>(h_b, 256, 4, wb2, cb2, rb2, h_a);

    pool_kernel<<<dim3(4, 32), 256, 0, stream>>>(h_a, poolpart);
    final_kernel<<<dim3(1), 256, 0, stream>>>(poolpart, fcw, fcb, mmdpart, dout);
}